// Round 5
// baseline (1284.317 us; speedup 1.0000x reference)
//
#include <hip/hip_runtime.h>
#include <hip/hip_fp16.h>

#define B_ 256
#define T_ 512
#define D_ 64
#define H_ 128
#define BB 16  // batches per recurrent block
#define CH 8   // time-chunk: one vmcnt drain per CH steps

typedef float f32x4 __attribute__((ext_vector_type(4)));
typedef short s16x4 __attribute__((ext_vector_type(4)));
typedef short s16x8 __attribute__((ext_vector_type(8)));
typedef __bf16 bf16x8 __attribute__((ext_vector_type(8)));
typedef _Float16 h16x4 __attribute__((ext_vector_type(4)));

template <typename AT> __device__ inline AT toAT(float x);
template <> __device__ inline float toAT<float>(float x) { return x; }
template <> __device__ inline __half toAT<__half>(float x) { return __float2half(x); }

template <typename AT> struct V4 {};
template <> struct V4<float> { typedef f32x4 type; };
template <> struct V4<__half> { typedef h16x4 type; };

__device__ inline float fsig(float x) {
  return __builtin_amdgcn_rcpf(1.f + __expf(-x));
}
__device__ inline float ftanh(float x) {
  return 1.f - 2.f * __builtin_amdgcn_rcpf(1.f + __expf(2.f * x));
}
__device__ inline short f2bf(float f) {  // RNE float->bf16
  unsigned u = __builtin_bit_cast(unsigned, f);
  u += 0x7fff + ((u >> 16) & 1);
  return (short)(u >> 16);
}

// ---------------------------------------------------------------------------
// Kernel 1 (unchanged): per-(b,t) pre-activations, layout A[row][4][H]
//   gate 0: G = exp(-relu(dlt @ w_gamma_h + b_gamma_h)) (pre-exponentiated)
//   gate 1: A_z, gate 2: A_r, gate 3: A_h
// ---------------------------------------------------------------------------
template <typename AT>
__global__ __launch_bounds__(256) void grud_pre(
    const float* __restrict__ values, const float* __restrict__ masks,
    const float* __restrict__ deltas, const float* __restrict__ emean,
    const float* __restrict__ locf,
    const float* __restrict__ w_gamma_x, const float* __restrict__ w_gamma_h,
    const float* __restrict__ w_rx, const float* __restrict__ w_rm,
    const float* __restrict__ w_zx, const float* __restrict__ w_zm,
    const float* __restrict__ w_hx, const float* __restrict__ w_hm,
    const float* __restrict__ b_gamma_x, const float* __restrict__ b_gamma_h,
    const float* __restrict__ b_r, const float* __restrict__ b_z,
    const float* __restrict__ b_h, AT* __restrict__ A) {
  __shared__ __align__(16) float xs[64][64];
  __shared__ __align__(16) float ms_[64][64];
  __shared__ float c_wg[64], c_bg[64], c_mn[64];

  const int tid = threadIdx.x;
  const int gate = blockIdx.y;
  const int rowbase = blockIdx.x * 64;
  const size_t base = (size_t)rowbase * D_;

  if (gate == 0) {
    const float4* dp = (const float4*)(deltas + base);
    for (int i = tid; i < 1024; i += 256) ((float4*)&xs[0][0])[i] = dp[i];
  } else {
    if (tid < 64) {
      c_wg[tid] = w_gamma_x[tid];
      c_bg[tid] = b_gamma_x[tid];
      c_mn[tid] = emean[tid];
    }
    __syncthreads();
    const float4* vp = (const float4*)(values + base);
    const float4* mp = (const float4*)(masks + base);
    const float4* dp = (const float4*)(deltas + base);
    const float4* lp = (const float4*)(locf + base);
    for (int i = tid; i < 1024; i += 256) {
      float4 v = vp[i], m = mp[i], dl = dp[i], l = lp[i];
      const int d0 = (i & 15) * 4;
      float vv[4] = {v.x, v.y, v.z, v.w};
      float mm[4] = {m.x, m.y, m.z, m.w};
      float dd[4] = {dl.x, dl.y, dl.z, dl.w};
      float ll[4] = {l.x, l.y, l.z, l.w};
      float xo[4];
#pragma unroll
      for (int j = 0; j < 4; ++j) {
        const int d = d0 + j;
        float gx = __expf(-fmaxf(c_wg[d] * dd[j] + c_bg[d], 0.f));
        xo[j] = mm[j] * vv[j] + (1.f - mm[j]) * (gx * ll[j] + (1.f - gx) * c_mn[d]);
      }
      ((float4*)&xs[0][0])[i] = make_float4(xo[0], xo[1], xo[2], xo[3]);
      ((float4*)&ms_[0][0])[i] = m;
    }
  }
  __syncthreads();

  const int col = tid & 127;
  const int rset = tid >> 7;
  const float* Wx;
  const float* Wm = nullptr;
  const float* bias;
  if (gate == 0) {
    Wx = w_gamma_h; bias = b_gamma_h;
  } else if (gate == 1) {
    Wx = w_zx; Wm = w_zm; bias = b_z;
  } else if (gate == 2) {
    Wx = w_rx; Wm = w_rm; bias = b_r;
  } else {
    Wx = w_hx; Wm = w_hm; bias = b_h;
  }

  float wx[64], wm[64];
#pragma unroll
  for (int k = 0; k < 64; ++k) wx[k] = Wx[k * H_ + col];
  if (gate != 0) {
#pragma unroll
    for (int k = 0; k < 64; ++k) wm[k] = Wm[k * H_ + col];
  }
  const float bv = bias[col];

  for (int r = 0; r < 32; ++r) {
    const int row = rset * 32 + r;
    float a0 = 0.f, a1 = 0.f, a2 = 0.f, a3 = 0.f;
    if (gate == 0) {
#pragma unroll
      for (int k4 = 0; k4 < 16; ++k4) {
        float4 xv = *(const float4*)&xs[row][k4 * 4];
        a0 += xv.x * wx[k4 * 4 + 0];
        a1 += xv.y * wx[k4 * 4 + 1];
        a2 += xv.z * wx[k4 * 4 + 2];
        a3 += xv.w * wx[k4 * 4 + 3];
      }
    } else {
#pragma unroll
      for (int k4 = 0; k4 < 16; ++k4) {
        float4 xv = *(const float4*)&xs[row][k4 * 4];
        float4 mv = *(const float4*)&ms_[row][k4 * 4];
        a0 += xv.x * wx[k4 * 4 + 0] + mv.x * wm[k4 * 4 + 0];
        a1 += xv.y * wx[k4 * 4 + 1] + mv.y * wm[k4 * 4 + 1];
        a2 += xv.z * wx[k4 * 4 + 2] + mv.z * wm[k4 * 4 + 2];
        a3 += xv.w * wx[k4 * 4 + 3] + mv.w * wm[k4 * 4 + 3];
      }
    }
    float acc = bv + ((a0 + a1) + (a2 + a3));
    if (gate == 0) acc = __expf(-fmaxf(acc, 0.f));
    A[(size_t)(rowbase + row) * (4 * H_) + gate * H_ + col] = toAT<AT>(acc);
  }
}

// ---------------------------------------------------------------------------
// Kernel 2: MFMA recurrence, time-chunked to beat the vmcnt(0)-drain at
// every s_barrier. 16 blocks x 16 batches, 512 threads (8 waves).
// Per chunk of CH=8 steps: issue all 36 A-row loads (9 steps x 4 gates,
// registers, fully static indexing) + flush previous chunk's 8 buffered hid
// stores -> exactly ONE vmem-drain exposure per chunk (at step 0's mid
// barrier); steps 1..7 run on LDS/MFMA/VALU only with cheap barriers.
// MFMA mapping unchanged from round 4 (verified passing):
//   D[n][m] = sum_k W[k][n]*h[m][k]; lane: batch=l&15, cols cb..cb+3.
// ---------------------------------------------------------------------------
template <typename AT>
__global__ __launch_bounds__(512, 1) void grud_rec_mfma(
    const AT* __restrict__ A, const float* __restrict__ w_zh,
    const float* __restrict__ w_rh, const float* __restrict__ w_hh,
    float* __restrict__ hid, float* __restrict__ hlast) {
  const int tid = threadIdx.x;
  const int w = tid >> 6;
  const int lane = tid & 63;
  const int bql = lane & 15;
  const int lg = lane >> 4;
  const int nbase = w * 16;
  const int cb = nbase + lg * 4;
  const int bb = blockIdx.x * BB;
  const int bg = bb + bql;

  __shared__ __align__(16) char lds[BB * 256 * 2 + BB * 512];
  char* h_bf = lds;          // [16][128] bf16, swizzled (4 KB)
  char* rh_bf = lds + 4096;  // [16][128] bf16, swizzled (4 KB)
  char* h_fp = lds + 8192;   // [16][128] fp32, swizzled (8 KB)

  // static weight A-frags: frag[tau], reg j = W[lg*8+j+32*tau][nbase+bql]
  s16x8 wz[4], wr[4], wh[4];
#pragma unroll
  for (int tau = 0; tau < 4; ++tau) {
    s16x8 az, ar, ah;
#pragma unroll
    for (int j = 0; j < 8; ++j) {
      const int k = lg * 8 + j + 32 * tau;
      az[j] = f2bf(w_zh[k * H_ + nbase + bql]);
      ar[j] = f2bf(w_rh[k * H_ + nbase + bql]);
      ah[j] = f2bf(w_hh[k * H_ + nbase + bql]);
    }
    wz[tau] = az; wr[tau] = ar; wh[tau] = ah;
  }

  // zero-init h state
  for (int i = tid; i < (int)sizeof(lds) / 16; i += 512)
    ((f32x4*)lds)[i] = f32x4{0.f, 0.f, 0.f, 0.f};

  // swizzled LDS byte offsets (lane constants)
  const int swz = (bql & 7) << 4;
  int off_rd[4];
#pragma unroll
  for (int tau = 0; tau < 4; ++tau)
    off_rd[tau] = bql * 256 + ((lg * 16 + tau * 64) ^ swz);
  const int off_bfw = bql * 256 + ((cb * 2) ^ swz);
  const int off_fp = bql * 512 + ((cb * 4) ^ swz);

  typedef typename V4<AT>::type v4t;
  const v4t* Arows = (const v4t*)A;
  const int ci = cb >> 2;

  f32x4 hbuf[CH];
  __syncthreads();

  for (int tc = 0; tc < T_; tc += CH) {
    // (1) issue this chunk's A-row loads first (latency-critical)
    v4t cur[CH + 1][4];
#pragma unroll
    for (int s = 0; s < CH + 1; ++s) {
      int t = tc + s;
      t = (t < T_) ? t : T_ - 1;
      const size_t r = ((size_t)bg * T_ + t) * 128 + ci;
      cur[s][0] = Arows[r];
      cur[s][1] = Arows[r + 32];
      cur[s][2] = Arows[r + 64];
      cur[s][3] = Arows[r + 96];
    }
    // (2) flush previous chunk's hid stores (drain overlapped with loads)
    if (tc > 0) {
#pragma unroll
      for (int s = 0; s < CH; ++s)
        *(f32x4*)(hid + ((size_t)bg * T_ + (tc - CH + s)) * H_ + cb) = hbuf[s];
    }

#pragma unroll
    for (int s = 0; s < CH; ++s) {
      const int t = tc + s;

      // P1: z/r matvecs over h_bf
      f32x4 Dz = {0.f, 0.f, 0.f, 0.f}, Dr = {0.f, 0.f, 0.f, 0.f};
#pragma unroll
      for (int tau = 0; tau < 4; ++tau) {
        s16x8 bh = *(const s16x8*)(h_bf + off_rd[tau]);
        Dz = __builtin_amdgcn_mfma_f32_16x16x32_bf16(
            __builtin_bit_cast(bf16x8, wz[tau]), __builtin_bit_cast(bf16x8, bh),
            Dz, 0, 0, 0);
        Dr = __builtin_amdgcn_mfma_f32_16x16x32_bf16(
            __builtin_bit_cast(bf16x8, wr[tau]), __builtin_bit_cast(bf16x8, bh),
            Dr, 0, 0, 0);
      }
      f32x4 hsc = *(const f32x4*)(h_fp + off_fp);

      f32x4 zzv;
      s16x4 rhv;
#pragma unroll
      for (int j = 0; j < 4; ++j) {
        zzv[j] = fsig((float)cur[s][1][j] + Dz[j]);
        float rr = fsig((float)cur[s][2][j] + Dr[j]);
        rhv[j] = f2bf(rr * hsc[j]);
      }
      *(s16x4*)(rh_bf + off_bfw) = rhv;
      __syncthreads();

      // P3: h_tilde matvec over rh_bf
      f32x4 Dh = {0.f, 0.f, 0.f, 0.f};
#pragma unroll
      for (int tau = 0; tau < 4; ++tau) {
        s16x8 brh = *(const s16x8*)(rh_bf + off_rd[tau]);
        Dh = __builtin_amdgcn_mfma_f32_16x16x32_bf16(
            __builtin_bit_cast(bf16x8, wh[tau]), __builtin_bit_cast(bf16x8, brh),
            Dh, 0, 0, 0);
      }

      f32x4 hgv;
      s16x4 hbv;
      f32x4 hnv;
#pragma unroll
      for (int j = 0; j < 4; ++j) {
        float ht = ftanh((float)cur[s][3][j] + Dh[j]);
        float hn = (1.f - zzv[j]) * hsc[j] + zzv[j] * ht;
        hnv[j] = hn;
        float hg = hn * (float)cur[s + 1][0][j];  // fold gamma_h(t+1)
        hgv[j] = hg;
        hbv[j] = f2bf(hg);
      }
      hbuf[s] = hnv;
      if (t < T_ - 1) {
        *(f32x4*)(h_fp + off_fp) = hgv;
        *(s16x4*)(h_bf + off_bfw) = hbv;
      }
      __syncthreads();
    }
  }

  // final chunk flush + hlast
#pragma unroll
  for (int s = 0; s < CH; ++s)
    *(f32x4*)(hid + ((size_t)bg * T_ + (T_ - CH + s)) * H_ + cb) = hbuf[s];
  *(f32x4*)(hlast + (size_t)bg * H_ + cb) = hbuf[CH - 1];
}

extern "C" void kernel_launch(void* const* d_in, const int* in_sizes, int n_in,
                              void* d_out, int out_size, void* d_ws, size_t ws_size,
                              hipStream_t stream) {
  const float* values = (const float*)d_in[0];
  const float* masks = (const float*)d_in[1];
  const float* deltas = (const float*)d_in[2];
  const float* emean = (const float*)d_in[3];
  const float* locf = (const float*)d_in[4];
  const float* w_gamma_x = (const float*)d_in[5];
  const float* w_gamma_h = (const float*)d_in[6];
  const float* w_rx = (const float*)d_in[7];
  const float* w_rh = (const float*)d_in[8];
  const float* w_rm = (const float*)d_in[9];
  const float* w_zx = (const float*)d_in[10];
  const float* w_zh = (const float*)d_in[11];
  const float* w_zm = (const float*)d_in[12];
  const float* w_hx = (const float*)d_in[13];
  const float* w_hh = (const float*)d_in[14];
  const float* w_hm = (const float*)d_in[15];
  const float* b_gamma_x = (const float*)d_in[16];
  const float* b_gamma_h = (const float*)d_in[17];
  const float* b_r = (const float*)d_in[18];
  const float* b_z = (const float*)d_in[19];
  const float* b_h = (const float*)d_in[20];

  float* hid = (float*)d_out;
  float* hlast = hid + (size_t)B_ * T_ * H_;

  dim3 gpre(B_ * T_ / 64, 4), bpre(256);
  dim3 grec(B_ / BB), brec(512);

  const size_t needH = (size_t)B_ * T_ * 4 * H_ * sizeof(__half);
  const size_t needF = (size_t)B_ * T_ * 4 * H_ * sizeof(float);
  if (ws_size >= needH) {
    __half* A = (__half*)d_ws;
    grud_pre<__half><<<gpre, bpre, 0, stream>>>(
        values, masks, deltas, emean, locf, w_gamma_x, w_gamma_h, w_rx, w_rm,
        w_zx, w_zm, w_hx, w_hm, b_gamma_x, b_gamma_h, b_r, b_z, b_h, A);
    grud_rec_mfma<__half><<<grec, brec, 0, stream>>>(A, w_zh, w_rh, w_hh, hid,
                                                     hlast);
  } else if (ws_size >= needF) {
    float* A = (float*)d_ws;
    grud_pre<float><<<gpre, bpre, 0, stream>>>(
        values, masks, deltas, emean, locf, w_gamma_x, w_gamma_h, w_rx, w_rm,
        w_zx, w_zm, w_hx, w_hm, b_gamma_x, b_gamma_h, b_r, b_z, b_h, A);
    grud_rec_mfma<float><<<grec, brec, 0, stream>>>(A, w_zh, w_rh, w_hh, hid,
                                                    hlast);
  }
}

// Round 7
// 1047.222 us; speedup vs baseline: 1.2264x; 1.2264x over previous
//
#include <hip/hip_runtime.h>
#include <hip/hip_fp16.h>

#define B_ 256
#define T_ 512
#define D_ 64
#define H_ 128
#define BB 16  // batches per recurrent block

typedef float f32x4 __attribute__((ext_vector_type(4)));
typedef short s16x4 __attribute__((ext_vector_type(4)));
typedef short s16x8 __attribute__((ext_vector_type(8)));
typedef __bf16 bf16x8 __attribute__((ext_vector_type(8)));
typedef _Float16 h16x4 __attribute__((ext_vector_type(4)));

template <typename AT> __device__ inline AT toAT(float x);
template <> __device__ inline float toAT<float>(float x) { return x; }
template <> __device__ inline __half toAT<__half>(float x) { return __float2half(x); }

template <typename AT> struct V4 {};
template <> struct V4<float> { typedef f32x4 type; };
template <> struct V4<__half> { typedef h16x4 type; };

__device__ inline float fsig(float x) {
  return __builtin_amdgcn_rcpf(1.f + __expf(-x));
}
__device__ inline float ftanh(float x) {
  return 1.f - 2.f * __builtin_amdgcn_rcpf(1.f + __expf(2.f * x));
}
__device__ inline short f2bf(float f) {  // RNE float->bf16
  unsigned u = __builtin_bit_cast(unsigned, f);
  u += 0x7fff + ((u >> 16) & 1);
  return (short)(u >> 16);
}

// Barrier that drains ONLY LDS ops: global loads/stores stay in flight.
// Safe here because all cross-wave communication is through LDS.
#define BAR()                                              \
  do {                                                     \
    asm volatile("s_waitcnt lgkmcnt(0)" ::: "memory");     \
    __builtin_amdgcn_s_barrier();                          \
  } while (0)

// ---------------------------------------------------------------------------
// Kernel 1 (unchanged): per-(b,t) pre-activations, layout A[row][4][H]
//   gate 0: G = exp(-relu(dlt @ w_gamma_h + b_gamma_h)) (pre-exponentiated)
//   gate 1: A_z, gate 2: A_r, gate 3: A_h
// ---------------------------------------------------------------------------
template <typename AT>
__global__ __launch_bounds__(256) void grud_pre(
    const float* __restrict__ values, const float* __restrict__ masks,
    const float* __restrict__ deltas, const float* __restrict__ emean,
    const float* __restrict__ locf,
    const float* __restrict__ w_gamma_x, const float* __restrict__ w_gamma_h,
    const float* __restrict__ w_rx, const float* __restrict__ w_rm,
    const float* __restrict__ w_zx, const float* __restrict__ w_zm,
    const float* __restrict__ w_hx, const float* __restrict__ w_hm,
    const float* __restrict__ b_gamma_x, const float* __restrict__ b_gamma_h,
    const float* __restrict__ b_r, const float* __restrict__ b_z,
    const float* __restrict__ b_h, AT* __restrict__ A) {
  __shared__ __align__(16) float xs[64][64];
  __shared__ __align__(16) float ms_[64][64];
  __shared__ float c_wg[64], c_bg[64], c_mn[64];

  const int tid = threadIdx.x;
  const int gate = blockIdx.y;
  const int rowbase = blockIdx.x * 64;
  const size_t base = (size_t)rowbase * D_;

  if (gate == 0) {
    const float4* dp = (const float4*)(deltas + base);
    for (int i = tid; i < 1024; i += 256) ((float4*)&xs[0][0])[i] = dp[i];
  } else {
    if (tid < 64) {
      c_wg[tid] = w_gamma_x[tid];
      c_bg[tid] = b_gamma_x[tid];
      c_mn[tid] = emean[tid];
    }
    __syncthreads();
    const float4* vp = (const float4*)(values + base);
    const float4* mp = (const float4*)(masks + base);
    const float4* dp = (const float4*)(deltas + base);
    const float4* lp = (const float4*)(locf + base);
    for (int i = tid; i < 1024; i += 256) {
      float4 v = vp[i], m = mp[i], dl = dp[i], l = lp[i];
      const int d0 = (i & 15) * 4;
      float vv[4] = {v.x, v.y, v.z, v.w};
      float mm[4] = {m.x, m.y, m.z, m.w};
      float dd[4] = {dl.x, dl.y, dl.z, dl.w};
      float ll[4] = {l.x, l.y, l.z, l.w};
      float xo[4];
#pragma unroll
      for (int j = 0; j < 4; ++j) {
        const int d = d0 + j;
        float gx = __expf(-fmaxf(c_wg[d] * dd[j] + c_bg[d], 0.f));
        xo[j] = mm[j] * vv[j] + (1.f - mm[j]) * (gx * ll[j] + (1.f - gx) * c_mn[d]);
      }
      ((float4*)&xs[0][0])[i] = make_float4(xo[0], xo[1], xo[2], xo[3]);
      ((float4*)&ms_[0][0])[i] = m;
    }
  }
  __syncthreads();

  const int col = tid & 127;
  const int rset = tid >> 7;
  const float* Wx;
  const float* Wm = nullptr;
  const float* bias;
  if (gate == 0) {
    Wx = w_gamma_h; bias = b_gamma_h;
  } else if (gate == 1) {
    Wx = w_zx; Wm = w_zm; bias = b_z;
  } else if (gate == 2) {
    Wx = w_rx; Wm = w_rm; bias = b_r;
  } else {
    Wx = w_hx; Wm = w_hm; bias = b_h;
  }

  float wx[64], wm[64];
#pragma unroll
  for (int k = 0; k < 64; ++k) wx[k] = Wx[k * H_ + col];
  if (gate != 0) {
#pragma unroll
    for (int k = 0; k < 64; ++k) wm[k] = Wm[k * H_ + col];
  }
  const float bv = bias[col];

  for (int r = 0; r < 32; ++r) {
    const int row = rset * 32 + r;
    float a0 = 0.f, a1 = 0.f, a2 = 0.f, a3 = 0.f;
    if (gate == 0) {
#pragma unroll
      for (int k4 = 0; k4 < 16; ++k4) {
        float4 xv = *(const float4*)&xs[row][k4 * 4];
        a0 += xv.x * wx[k4 * 4 + 0];
        a1 += xv.y * wx[k4 * 4 + 1];
        a2 += xv.z * wx[k4 * 4 + 2];
        a3 += xv.w * wx[k4 * 4 + 3];
      }
    } else {
#pragma unroll
      for (int k4 = 0; k4 < 16; ++k4) {
        float4 xv = *(const float4*)&xs[row][k4 * 4];
        float4 mv = *(const float4*)&ms_[row][k4 * 4];
        a0 += xv.x * wx[k4 * 4 + 0] + mv.x * wm[k4 * 4 + 0];
        a1 += xv.y * wx[k4 * 4 + 1] + mv.y * wm[k4 * 4 + 1];
        a2 += xv.z * wx[k4 * 4 + 2] + mv.z * wm[k4 * 4 + 2];
        a3 += xv.w * wx[k4 * 4 + 3] + mv.w * wm[k4 * 4 + 3];
      }
    }
    float acc = bv + ((a0 + a1) + (a2 + a3));
    if (gate == 0) acc = __expf(-fmaxf(acc, 0.f));
    A[(size_t)(rowbase + row) * (4 * H_) + gate * H_ + col] = toAT<AT>(acc);
  }
}

// ---------------------------------------------------------------------------
// Kernel 2: MFMA recurrence. 16 blocks x 16 batches, 512 threads (8 waves).
// Wave w owns output cols [w*16, w*16+16).  D[n][m] = sum_k W[k][n]*h[m][k].
// Changes vs r5:
//  - raw barriers (lgkmcnt-only): A-loads + hid-stores never drained
//  - LDS holds h/rh in MFMA-B-FRAGMENT ORDER: reads are linear
//    ds_read_b128 at tau*1024 + lane*16 (conflict-free); each lane scatters
//    its 4 cols with one ds_write_b64 at a statically-derived address.
//    Mapping (verified bijective): writer (w,b,q), cols 16w+4q+{0..3} ->
//    byte (w>>1)*1024 + (b+16*((2w+(q>>1))&3))*16 + 8*(q&1).
//  - h state lives in registers (hsc), no fp32 LDS copy.
// ---------------------------------------------------------------------------
template <typename AT>
__global__ __launch_bounds__(512, 1) void grud_rec_mfma(
    const AT* __restrict__ A, const float* __restrict__ w_zh,
    const float* __restrict__ w_rh, const float* __restrict__ w_hh,
    float* __restrict__ hid, float* __restrict__ hlast) {
  const int tid = threadIdx.x;
  const int w = tid >> 6;
  const int lane = tid & 63;
  const int b = lane & 15;   // batch within block (D col, A row)
  const int q = lane >> 4;   // 0..3
  const int cb = w * 16 + q * 4;       // this lane's 4 output cols
  const int bg = blockIdx.x * BB + b;  // global batch

  __shared__ __align__(16) char lds[8192];
  char* h_bf = lds;          // [4 tau][64 lane][16B]  (4 KB)
  char* rh_bf = lds + 4096;  // same layout            (4 KB)

  // A-frags: frag tau, reg j = W[q*8+j+32*tau][w*16+b] (bf16)
  s16x8 wzf[4], wrf[4], whf[4];
#pragma unroll
  for (int tau = 0; tau < 4; ++tau) {
    s16x8 az, ar, ah;
#pragma unroll
    for (int j = 0; j < 8; ++j) {
      const int k = q * 8 + j + 32 * tau;
      az[j] = f2bf(w_zh[k * H_ + w * 16 + b]);
      ar[j] = f2bf(w_rh[k * H_ + w * 16 + b]);
      ah[j] = f2bf(w_hh[k * H_ + w * 16 + b]);
    }
    wzf[tau] = az; wrf[tau] = ar; whf[tau] = ah;
  }

  // zero LDS (h = 0 at t = 0)
  for (int i = tid; i < 8192 / 16; i += 512)
    ((f32x4*)lds)[i] = f32x4{0.f, 0.f, 0.f, 0.f};

  int off_rd[4];
#pragma unroll
  for (int tau = 0; tau < 4; ++tau) off_rd[tau] = tau * 1024 + lane * 16;
  const int off_wr =
      (w >> 1) * 1024 + (b + 16 * ((2 * w + (q >> 1)) & 3)) * 16 + 8 * (q & 1);

  typedef typename V4<AT>::type v4t;
  const v4t* Arows = (const v4t*)A;
  const int ci = cb >> 2;  // vec4 index within a 128-col gate block

  v4t c0[4], c1[4];  // pre-activation rows for t and t+1: [G, Az, Ar, Ah]
  {
    const size_t r0 = ((size_t)bg * T_ + 0) * 128 + ci;
    c0[0] = Arows[r0]; c0[1] = Arows[r0 + 32];
    c0[2] = Arows[r0 + 64]; c0[3] = Arows[r0 + 96];
    const size_t r1 = ((size_t)bg * T_ + (T_ > 1 ? 1 : 0)) * 128 + ci;
    c1[0] = Arows[r1]; c1[1] = Arows[r1 + 32];
    c1[2] = Arows[r1 + 64]; c1[3] = Arows[r1 + 96];
  }
  f32x4 hsc = {0.f, 0.f, 0.f, 0.f};  // gamma_h(t) * h(t-1), this lane's 4 cols
  __syncthreads();  // one full barrier at start is fine

  for (int t = 0; t < T_; ++t) {
    // prefetch row t+2 (stays in flight across raw barriers)
    v4t c2[4];
    {
      const int t2 = (t + 2 < T_) ? t + 2 : T_ - 1;
      const size_t r = ((size_t)bg * T_ + t2) * 128 + ci;
      c2[0] = Arows[r]; c2[1] = Arows[r + 32];
      c2[2] = Arows[r + 64]; c2[3] = Arows[r + 96];
    }

    // P1: z/r matvecs over h_bf (linear conflict-free reads)
    f32x4 Dz = {0.f, 0.f, 0.f, 0.f}, Dr = {0.f, 0.f, 0.f, 0.f};
#pragma unroll
    for (int tau = 0; tau < 4; ++tau) {
      s16x8 bh = *(const s16x8*)(h_bf + off_rd[tau]);
      Dz = __builtin_amdgcn_mfma_f32_16x16x32_bf16(
          __builtin_bit_cast(bf16x8, wzf[tau]), __builtin_bit_cast(bf16x8, bh),
          Dz, 0, 0, 0);
      Dr = __builtin_amdgcn_mfma_f32_16x16x32_bf16(
          __builtin_bit_cast(bf16x8, wrf[tau]), __builtin_bit_cast(bf16x8, bh),
          Dr, 0, 0, 0);
    }

    f32x4 zz;
    s16x4 rhv;
#pragma unroll
    for (int j = 0; j < 4; ++j) {
      zz[j] = fsig((float)c0[1][j] + Dz[j]);
      float rr = fsig((float)c0[2][j] + Dr[j]);
      rhv[j] = f2bf(rr * hsc[j]);
    }
    *(s16x4*)(rh_bf + off_wr) = rhv;
    BAR();

    // P2: h_tilde matvec over rh_bf
    f32x4 Dh = {0.f, 0.f, 0.f, 0.f};
#pragma unroll
    for (int tau = 0; tau < 4; ++tau) {
      s16x8 brh = *(const s16x8*)(rh_bf + off_rd[tau]);
      Dh = __builtin_amdgcn_mfma_f32_16x16x32_bf16(
          __builtin_bit_cast(bf16x8, whf[tau]), __builtin_bit_cast(bf16x8, brh),
          Dh, 0, 0, 0);
    }

    f32x4 hnv;
    s16x4 hbv;
#pragma unroll
    for (int j = 0; j < 4; ++j) {
      float ht = ftanh((float)c0[3][j] + Dh[j]);
      float hn = (1.f - zz[j]) * hsc[j] + zz[j] * ht;
      hnv[j] = hn;
      float hg = hn * (float)c1[0][j];  // fold gamma_h(t+1)
      hsc[j] = hg;
      hbv[j] = f2bf(hg);
    }
    *(f32x4*)(hid + ((size_t)bg * T_ + t) * H_ + cb) = hnv;  // fire-and-forget
    if (t == T_ - 1) *(f32x4*)(hlast + (size_t)bg * H_ + cb) = hnv;
    *(s16x4*)(h_bf + off_wr) = hbv;
    BAR();

#pragma unroll
    for (int i = 0; i < 4; ++i) { c0[i] = c1[i]; c1[i] = c2[i]; }
  }
}

extern "C" void kernel_launch(void* const* d_in, const int* in_sizes, int n_in,
                              void* d_out, int out_size, void* d_ws, size_t ws_size,
                              hipStream_t stream) {
  const float* values = (const float*)d_in[0];
  const float* masks = (const float*)d_in[1];
  const float* deltas = (const float*)d_in[2];
  const float* emean = (const float*)d_in[3];
  const float* locf = (const float*)d_in[4];
  const float* w_gamma_x = (const float*)d_in[5];
  const float* w_gamma_h = (const float*)d_in[6];
  const float* w_rx = (const float*)d_in[7];
  const float* w_rh = (const float*)d_in[8];
  const float* w_rm = (const float*)d_in[9];
  const float* w_zx = (const float*)d_in[10];
  const float* w_zh = (const float*)d_in[11];
  const float* w_zm = (const float*)d_in[12];
  const float* w_hx = (const float*)d_in[13];
  const float* w_hh = (const float*)d_in[14];
  const float* w_hm = (const float*)d_in[15];
  const float* b_gamma_x = (const float*)d_in[16];
  const float* b_gamma_h = (const float*)d_in[17];
  const float* b_r = (const float*)d_in[18];
  const float* b_z = (const float*)d_in[19];
  const float* b_h = (const float*)d_in[20];

  float* hid = (float*)d_out;
  float* hlast = hid + (size_t)B_ * T_ * H_;

  dim3 gpre(B_ * T_ / 64, 4), bpre(256);
  dim3 grec(B_ / BB), brec(512);

  const size_t needH = (size_t)B_ * T_ * 4 * H_ * sizeof(__half);
  const size_t needF = (size_t)B_ * T_ * 4 * H_ * sizeof(float);
  if (ws_size >= needH) {
    __half* A = (__half*)d_ws;
    grud_pre<__half><<<gpre, bpre, 0, stream>>>(
        values, masks, deltas, emean, locf, w_gamma_x, w_gamma_h, w_rx, w_rm,
        w_zx, w_zm, w_hx, w_hm, b_gamma_x, b_gamma_h, b_r, b_z, b_h, A);
    grud_rec_mfma<__half><<<grec, brec, 0, stream>>>(A, w_zh, w_rh, w_hh, hid,
                                                     hlast);
  } else if (ws_size >= needF) {
    float* A = (float*)d_ws;
    grud_pre<float><<<gpre, bpre, 0, stream>>>(
        values, masks, deltas, emean, locf, w_gamma_x, w_gamma_h, w_rx, w_rm,
        w_zx, w_zm, w_hx, w_hm, b_gamma_x, b_gamma_h, b_r, b_z, b_h, A);
    grud_rec_mfma<float><<<grec, brec, 0, stream>>>(A, w_zh, w_rh, w_hh, hid,
                                                    hlast);
  }
}

// Round 8
// 911.184 us; speedup vs baseline: 1.4095x; 1.1493x over previous
//
#include <hip/hip_runtime.h>
#include <hip/hip_fp16.h>

#define B_ 256
#define T_ 512
#define D_ 64
#define H_ 128
#define BB 16  // batches per recurrent block

typedef float f32x4 __attribute__((ext_vector_type(4)));
typedef short s16x4 __attribute__((ext_vector_type(4)));
typedef short s16x8 __attribute__((ext_vector_type(8)));
typedef __bf16 bf16x8 __attribute__((ext_vector_type(8)));
typedef _Float16 h16x4 __attribute__((ext_vector_type(4)));

template <typename AT> __device__ inline AT toAT(float x);
template <> __device__ inline float toAT<float>(float x) { return x; }
template <> __device__ inline __half toAT<__half>(float x) { return __float2half(x); }

template <typename AT> struct V4 {};
template <> struct V4<float> { typedef f32x4 type; };
template <> struct V4<__half> { typedef h16x4 type; };

__device__ inline float fsig(float x) {
  return __builtin_amdgcn_rcpf(1.f + __expf(-x));
}
__device__ inline float ftanh(float x) {
  return 1.f - 2.f * __builtin_amdgcn_rcpf(1.f + __expf(2.f * x));
}
__device__ inline short f2bf(float f) {  // RNE float->bf16
  unsigned u = __builtin_bit_cast(unsigned, f);
  u += 0x7fff + ((u >> 16) & 1);
  return (short)(u >> 16);
}
__device__ __forceinline__ f32x4 MF(s16x8 a, s16x8 b, f32x4 c) {
  return __builtin_amdgcn_mfma_f32_16x16x32_bf16(
      __builtin_bit_cast(bf16x8, a), __builtin_bit_cast(bf16x8, b), c, 0, 0, 0);
}

// Barrier that drains ONLY LDS ops: global loads/stores stay in flight.
// Safe here because all cross-wave communication is through LDS.
#define BAR()                                              \
  do {                                                     \
    asm volatile("s_waitcnt lgkmcnt(0)" ::: "memory");     \
    __builtin_amdgcn_s_barrier();                          \
  } while (0)

// ---------------------------------------------------------------------------
// Kernel 1 (unchanged): per-(b,t) pre-activations, layout A[row][4][H]
//   gate 0: G = exp(-relu(dlt @ w_gamma_h + b_gamma_h)) (pre-exponentiated)
//   gate 1: A_z, gate 2: A_r, gate 3: A_h
// ---------------------------------------------------------------------------
template <typename AT>
__global__ __launch_bounds__(256) void grud_pre(
    const float* __restrict__ values, const float* __restrict__ masks,
    const float* __restrict__ deltas, const float* __restrict__ emean,
    const float* __restrict__ locf,
    const float* __restrict__ w_gamma_x, const float* __restrict__ w_gamma_h,
    const float* __restrict__ w_rx, const float* __restrict__ w_rm,
    const float* __restrict__ w_zx, const float* __restrict__ w_zm,
    const float* __restrict__ w_hx, const float* __restrict__ w_hm,
    const float* __restrict__ b_gamma_x, const float* __restrict__ b_gamma_h,
    const float* __restrict__ b_r, const float* __restrict__ b_z,
    const float* __restrict__ b_h, AT* __restrict__ A) {
  __shared__ __align__(16) float xs[64][64];
  __shared__ __align__(16) float ms_[64][64];
  __shared__ float c_wg[64], c_bg[64], c_mn[64];

  const int tid = threadIdx.x;
  const int gate = blockIdx.y;
  const int rowbase = blockIdx.x * 64;
  const size_t base = (size_t)rowbase * D_;

  if (gate == 0) {
    const float4* dp = (const float4*)(deltas + base);
    for (int i = tid; i < 1024; i += 256) ((float4*)&xs[0][0])[i] = dp[i];
  } else {
    if (tid < 64) {
      c_wg[tid] = w_gamma_x[tid];
      c_bg[tid] = b_gamma_x[tid];
      c_mn[tid] = emean[tid];
    }
    __syncthreads();
    const float4* vp = (const float4*)(values + base);
    const float4* mp = (const float4*)(masks + base);
    const float4* dp = (const float4*)(deltas + base);
    const float4* lp = (const float4*)(locf + base);
    for (int i = tid; i < 1024; i += 256) {
      float4 v = vp[i], m = mp[i], dl = dp[i], l = lp[i];
      const int d0 = (i & 15) * 4;
      float vv[4] = {v.x, v.y, v.z, v.w};
      float mm[4] = {m.x, m.y, m.z, m.w};
      float dd[4] = {dl.x, dl.y, dl.z, dl.w};
      float ll[4] = {l.x, l.y, l.z, l.w};
      float xo[4];
#pragma unroll
      for (int j = 0; j < 4; ++j) {
        const int d = d0 + j;
        float gx = __expf(-fmaxf(c_wg[d] * dd[j] + c_bg[d], 0.f));
        xo[j] = mm[j] * vv[j] + (1.f - mm[j]) * (gx * ll[j] + (1.f - gx) * c_mn[d]);
      }
      ((float4*)&xs[0][0])[i] = make_float4(xo[0], xo[1], xo[2], xo[3]);
      ((float4*)&ms_[0][0])[i] = m;
    }
  }
  __syncthreads();

  const int col = tid & 127;
  const int rset = tid >> 7;
  const float* Wx;
  const float* Wm = nullptr;
  const float* bias;
  if (gate == 0) {
    Wx = w_gamma_h; bias = b_gamma_h;
  } else if (gate == 1) {
    Wx = w_zx; Wm = w_zm; bias = b_z;
  } else if (gate == 2) {
    Wx = w_rx; Wm = w_rm; bias = b_r;
  } else {
    Wx = w_hx; Wm = w_hm; bias = b_h;
  }

  float wx[64], wm[64];
#pragma unroll
  for (int k = 0; k < 64; ++k) wx[k] = Wx[k * H_ + col];
  if (gate != 0) {
#pragma unroll
    for (int k = 0; k < 64; ++k) wm[k] = Wm[k * H_ + col];
  }
  const float bv = bias[col];

  for (int r = 0; r < 32; ++r) {
    const int row = rset * 32 + r;
    float a0 = 0.f, a1 = 0.f, a2 = 0.f, a3 = 0.f;
    if (gate == 0) {
#pragma unroll
      for (int k4 = 0; k4 < 16; ++k4) {
        float4 xv = *(const float4*)&xs[row][k4 * 4];
        a0 += xv.x * wx[k4 * 4 + 0];
        a1 += xv.y * wx[k4 * 4 + 1];
        a2 += xv.z * wx[k4 * 4 + 2];
        a3 += xv.w * wx[k4 * 4 + 3];
      }
    } else {
#pragma unroll
      for (int k4 = 0; k4 < 16; ++k4) {
        float4 xv = *(const float4*)&xs[row][k4 * 4];
        float4 mv = *(const float4*)&ms_[row][k4 * 4];
        a0 += xv.x * wx[k4 * 4 + 0] + mv.x * wm[k4 * 4 + 0];
        a1 += xv.y * wx[k4 * 4 + 1] + mv.y * wm[k4 * 4 + 1];
        a2 += xv.z * wx[k4 * 4 + 2] + mv.z * wm[k4 * 4 + 2];
        a3 += xv.w * wx[k4 * 4 + 3] + mv.w * wm[k4 * 4 + 3];
      }
    }
    float acc = bv + ((a0 + a1) + (a2 + a3));
    if (gate == 0) acc = __expf(-fmaxf(acc, 0.f));
    A[(size_t)(rowbase + row) * (4 * H_) + gate * H_ + col] = toAT<AT>(acc);
  }
}

// ---------------------------------------------------------------------------
// Kernel 2: MFMA recurrence. 16 blocks x 16 batches, 512 threads (8 waves).
// Wave w owns output cols [w*16, w*16+16).  D[n][m] = sum_k W[k][n]*h[m][k].
// vs r7: time loop unrolled x4 with four NAMED register buffers b0..b3
// (no loop-carried register rotation!). At the top of step t we copy CUR's
// rows to temps (loaded 4 steps ago -> resident) and immediately re-issue
// CUR's loads for t+4: first use is ~4 steps later, so L3/HBM latency never
// lands on the critical path. MFMA accumulate chains split 4 -> 2+2.
// LDS B-fragment layout + lgkm-only barriers unchanged (bijective scatter:
// writer (w,b,q) -> byte (w>>1)*1024 + (b+16*((2w+(q>>1))&3))*16 + 8*(q&1)).
// ---------------------------------------------------------------------------
#define STEP(T0, CUR, NXT)                                                  \
  do {                                                                      \
    const int t_ = (T0);                                                    \
    v4t tAz = CUR[1], tAr = CUR[2], tAh = CUR[3];                           \
    { /* re-issue CUR <- rows t+4 (consumed 4 steps from now) */            \
      const int t4 = (t_ + 4 < T_) ? t_ + 4 : T_ - 1;                       \
      const size_t r = ((size_t)bg * T_ + t4) * 128 + ci;                   \
      CUR[0] = Arows[r];       CUR[1] = Arows[r + 32];                      \
      CUR[2] = Arows[r + 64];  CUR[3] = Arows[r + 96];                      \
    }                                                                       \
    f32x4 Dz0 = {0,0,0,0}, Dz1 = {0,0,0,0};                                 \
    f32x4 Dr0 = {0,0,0,0}, Dr1 = {0,0,0,0};                                 \
    {                                                                       \
      s16x8 bh0 = *(const s16x8*)(h_bf + off_rd[0]);                        \
      s16x8 bh1 = *(const s16x8*)(h_bf + off_rd[1]);                        \
      s16x8 bh2 = *(const s16x8*)(h_bf + off_rd[2]);                        \
      s16x8 bh3 = *(const s16x8*)(h_bf + off_rd[3]);                        \
      Dz0 = MF(wzf[0], bh0, Dz0); Dr0 = MF(wrf[0], bh0, Dr0);               \
      Dz1 = MF(wzf[2], bh2, Dz1); Dr1 = MF(wrf[2], bh2, Dr1);               \
      Dz0 = MF(wzf[1], bh1, Dz0); Dr0 = MF(wrf[1], bh1, Dr0);               \
      Dz1 = MF(wzf[3], bh3, Dz1); Dr1 = MF(wrf[3], bh3, Dr1);               \
    }                                                                       \
    f32x4 zz;                                                               \
    s16x4 rhv;                                                              \
    _Pragma("unroll")                                                       \
    for (int j = 0; j < 4; ++j) {                                           \
      zz[j] = fsig((float)tAz[j] + (Dz0[j] + Dz1[j]));                      \
      float rr = fsig((float)tAr[j] + (Dr0[j] + Dr1[j]));                   \
      rhv[j] = f2bf(rr * hsc[j]);                                           \
    }                                                                       \
    *(s16x4*)(rh_bf + off_wr) = rhv;                                        \
    BAR();                                                                  \
    f32x4 Dh0 = {0,0,0,0}, Dh1 = {0,0,0,0};                                 \
    {                                                                       \
      s16x8 p0 = *(const s16x8*)(rh_bf + off_rd[0]);                        \
      s16x8 p1 = *(const s16x8*)(rh_bf + off_rd[1]);                        \
      s16x8 p2 = *(const s16x8*)(rh_bf + off_rd[2]);                        \
      s16x8 p3 = *(const s16x8*)(rh_bf + off_rd[3]);                        \
      Dh0 = MF(whf[0], p0, Dh0); Dh1 = MF(whf[2], p2, Dh1);                 \
      Dh0 = MF(whf[1], p1, Dh0); Dh1 = MF(whf[3], p3, Dh1);                 \
    }                                                                       \
    f32x4 hnv;                                                              \
    s16x4 hbv;                                                              \
    _Pragma("unroll")                                                       \
    for (int j = 0; j < 4; ++j) {                                           \
      float ht = ftanh((float)tAh[j] + (Dh0[j] + Dh1[j]));                  \
      float hn = (1.f - zz[j]) * hsc[j] + zz[j] * ht;                       \
      hnv[j] = hn;                                                          \
      float hg = hn * (float)NXT[0][j]; /* fold gamma_h(t+1) */             \
      hsc[j] = hg;                                                          \
      hbv[j] = f2bf(hg);                                                    \
    }                                                                       \
    *(f32x4*)(hid + ((size_t)bg * T_ + t_) * H_ + cb) = hnv;                \
    if (t_ == T_ - 1) *(f32x4*)(hlast + (size_t)bg * H_ + cb) = hnv;        \
    *(s16x4*)(h_bf + off_wr) = hbv;                                         \
    BAR();                                                                  \
  } while (0)

template <typename AT>
__global__ __launch_bounds__(512, 1) void grud_rec_mfma(
    const AT* __restrict__ A, const float* __restrict__ w_zh,
    const float* __restrict__ w_rh, const float* __restrict__ w_hh,
    float* __restrict__ hid, float* __restrict__ hlast) {
  const int tid = threadIdx.x;
  const int w = tid >> 6;
  const int lane = tid & 63;
  const int b = lane & 15;   // batch within block (D col, A row)
  const int q = lane >> 4;   // 0..3
  const int cb = w * 16 + q * 4;       // this lane's 4 output cols
  const int bg = blockIdx.x * BB + b;  // global batch

  __shared__ __align__(16) char lds[8192];
  char* h_bf = lds;          // [4 tau][64 lane][16B]  (4 KB)
  char* rh_bf = lds + 4096;  // same layout            (4 KB)

  // A-frags: frag tau, reg j = W[q*8+j+32*tau][w*16+b] (bf16)
  s16x8 wzf[4], wrf[4], whf[4];
#pragma unroll
  for (int tau = 0; tau < 4; ++tau) {
    s16x8 az, ar, ah;
#pragma unroll
    for (int j = 0; j < 8; ++j) {
      const int k = q * 8 + j + 32 * tau;
      az[j] = f2bf(w_zh[k * H_ + w * 16 + b]);
      ar[j] = f2bf(w_rh[k * H_ + w * 16 + b]);
      ah[j] = f2bf(w_hh[k * H_ + w * 16 + b]);
    }
    wzf[tau] = az; wrf[tau] = ar; whf[tau] = ah;
  }

  // zero LDS (h = 0 at t = 0)
  for (int i = tid; i < 8192 / 16; i += 512)
    ((f32x4*)lds)[i] = f32x4{0.f, 0.f, 0.f, 0.f};

  int off_rd[4];
#pragma unroll
  for (int tau = 0; tau < 4; ++tau) off_rd[tau] = tau * 1024 + lane * 16;
  const int off_wr =
      (w >> 1) * 1024 + (b + 16 * ((2 * w + (q >> 1)) & 3)) * 16 + 8 * (q & 1);

  typedef typename V4<AT>::type v4t;
  const v4t* Arows = (const v4t*)A;
  const int ci = cb >> 2;  // vec4 index within a 128-col gate block

  // four named prefetch buffers, rows t=0..3 (statically indexed throughout)
  v4t b0[4], b1[4], b2[4], b3[4];
  {
    const size_t r0 = ((size_t)bg * T_ + 0) * 128 + ci;
    b0[0] = Arows[r0]; b0[1] = Arows[r0 + 32];
    b0[2] = Arows[r0 + 64]; b0[3] = Arows[r0 + 96];
    const size_t r1 = ((size_t)bg * T_ + 1) * 128 + ci;
    b1[0] = Arows[r1]; b1[1] = Arows[r1 + 32];
    b1[2] = Arows[r1 + 64]; b1[3] = Arows[r1 + 96];
    const size_t r2 = ((size_t)bg * T_ + 2) * 128 + ci;
    b2[0] = Arows[r2]; b2[1] = Arows[r2 + 32];
    b2[2] = Arows[r2 + 64]; b2[3] = Arows[r2 + 96];
    const size_t r3 = ((size_t)bg * T_ + 3) * 128 + ci;
    b3[0] = Arows[r3]; b3[1] = Arows[r3 + 32];
    b3[2] = Arows[r3 + 64]; b3[3] = Arows[r3 + 96];
  }
  f32x4 hsc = {0.f, 0.f, 0.f, 0.f};  // gamma_h(t) * h(t-1), this lane's 4 cols
  __syncthreads();  // one full barrier at start is fine

  for (int tp = 0; tp < T_; tp += 4) {
    STEP(tp + 0, b0, b1);
    STEP(tp + 1, b1, b2);
    STEP(tp + 2, b2, b3);
    STEP(tp + 3, b3, b0);
  }
}

extern "C" void kernel_launch(void* const* d_in, const int* in_sizes, int n_in,
                              void* d_out, int out_size, void* d_ws, size_t ws_size,
                              hipStream_t stream) {
  const float* values = (const float*)d_in[0];
  const float* masks = (const float*)d_in[1];
  const float* deltas = (const float*)d_in[2];
  const float* emean = (const float*)d_in[3];
  const float* locf = (const float*)d_in[4];
  const float* w_gamma_x = (const float*)d_in[5];
  const float* w_gamma_h = (const float*)d_in[6];
  const float* w_rx = (const float*)d_in[7];
  const float* w_rh = (const float*)d_in[8];
  const float* w_rm = (const float*)d_in[9];
  const float* w_zx = (const float*)d_in[10];
  const float* w_zh = (const float*)d_in[11];
  const float* w_zm = (const float*)d_in[12];
  const float* w_hx = (const float*)d_in[13];
  const float* w_hh = (const float*)d_in[14];
  const float* w_hm = (const float*)d_in[15];
  const float* b_gamma_x = (const float*)d_in[16];
  const float* b_gamma_h = (const float*)d_in[17];
  const float* b_r = (const float*)d_in[18];
  const float* b_z = (const float*)d_in[19];
  const float* b_h = (const float*)d_in[20];

  float* hid = (float*)d_out;
  float* hlast = hid + (size_t)B_ * T_ * H_;

  dim3 gpre(B_ * T_ / 64, 4), bpre(256);
  dim3 grec(B_ / BB), brec(512);

  const size_t needH = (size_t)B_ * T_ * 4 * H_ * sizeof(__half);
  const size_t needF = (size_t)B_ * T_ * 4 * H_ * sizeof(float);
  if (ws_size >= needH) {
    __half* A = (__half*)d_ws;
    grud_pre<__half><<<gpre, bpre, 0, stream>>>(
        values, masks, deltas, emean, locf, w_gamma_x, w_gamma_h, w_rx, w_rm,
        w_zx, w_zm, w_hx, w_hm, b_gamma_x, b_gamma_h, b_r, b_z, b_h, A);
    grud_rec_mfma<__half><<<grec, brec, 0, stream>>>(A, w_zh, w_rh, w_hh, hid,
                                                     hlast);
  } else if (ws_size >= needF) {
    float* A = (float*)d_ws;
    grud_pre<float><<<gpre, bpre, 0, stream>>>(
        values, masks, deltas, emean, locf, w_gamma_x, w_gamma_h, w_rx, w_rm,
        w_zx, w_zm, w_hx, w_hm, b_gamma_x, b_gamma_h, b_r, b_z, b_h, A);
    grud_rec_mfma<float><<<grec, brec, 0, stream>>>(A, w_zh, w_rh, w_hh, hid,
                                                    hlast);
  }
}

// Round 9
// 755.337 us; speedup vs baseline: 1.7003x; 1.2063x over previous
//
#include <hip/hip_runtime.h>
#include <hip/hip_fp16.h>

#define B_ 256
#define T_ 512
#define D_ 64
#define H_ 128
#define BB 16  // batches per recurrent block

typedef float f32x4 __attribute__((ext_vector_type(4)));
typedef short s16x4 __attribute__((ext_vector_type(4)));
typedef short s16x8 __attribute__((ext_vector_type(8)));
typedef __bf16 bf16x8 __attribute__((ext_vector_type(8)));
typedef _Float16 h16x4 __attribute__((ext_vector_type(4)));
typedef _Float16 f16x8v __attribute__((ext_vector_type(8)));

__device__ unsigned short g_W16[7 * 8 * 2 * 512];  // fp16 B-frag-ordered weights
__device__ float g_bias[512];                      // [G,z,r,h] biases

__device__ inline float toF(__half x) { return __half2float(x); }

__device__ inline float fsig(float x) {
  return __builtin_amdgcn_rcpf(1.f + __expf(-x));
}
__device__ inline float ftanh(float x) {
  return 1.f - 2.f * __builtin_amdgcn_rcpf(1.f + __expf(2.f * x));
}
__device__ inline short f2bf(float f) {  // RNE float->bf16
  unsigned u = __builtin_bit_cast(unsigned, f);
  u += 0x7fff + ((u >> 16) & 1);
  return (short)(u >> 16);
}
__device__ __forceinline__ f32x4 MF(s16x8 a, s16x8 b, f32x4 c) {
  return __builtin_amdgcn_mfma_f32_16x16x32_bf16(
      __builtin_bit_cast(bf16x8, a), __builtin_bit_cast(bf16x8, b), c, 0, 0, 0);
}
__device__ __forceinline__ f32x4 MFH(f16x8v a, s16x8 b, f32x4 c) {
  return __builtin_amdgcn_mfma_f32_16x16x32_f16(
      a, __builtin_bit_cast(f16x8v, b), c, 0, 0, 0);
}

// Barrier draining ONLY LDS ops: global loads/stores stay in flight.
#define BAR()                                              \
  do {                                                     \
    asm volatile("s_waitcnt lgkmcnt(0)" ::: "memory");     \
    __builtin_amdgcn_s_barrier();                          \
  } while (0)

// ---------------------------------------------------------------------------
// Kernel 0: weight prep. Converts the 7 [64][128] fp32 matrices into fp16
// B-fragment order (value = W[k=8*(l>>4)+j+32*tau][col=ct*16+(l&15)]) and
// builds the 512-entry bias vector, both in __device__ globals.
// Matrix order: 0=w_gamma_h, 1=w_zx, 2=w_zm, 3=w_rx, 4=w_rm, 5=w_hx, 6=w_hm.
// ---------------------------------------------------------------------------
__global__ __launch_bounds__(64) void wprep(
    const float* __restrict__ wgh, const float* __restrict__ wzx,
    const float* __restrict__ wzm, const float* __restrict__ wrx,
    const float* __restrict__ wrm, const float* __restrict__ whx,
    const float* __restrict__ whm, const float* __restrict__ bgh,
    const float* __restrict__ bz, const float* __restrict__ br,
    const float* __restrict__ bh) {
  const int g = blockIdx.x, l = threadIdx.x;
  if (g < 112) {
    const float* mats[7] = {wgh, wzx, wzm, wrx, wrm, whx, whm};
    const int mat = g >> 4, sub = g & 15, ct = sub >> 1, tau = sub & 1;
    const float* W = mats[mat];
    const int base = ((mat * 8 + ct) * 2 + tau) * 512 + l * 8;
#pragma unroll
    for (int j = 0; j < 8; ++j) {
      const int k = 8 * (l >> 4) + j + 32 * tau;
      const int col = ct * 16 + (l & 15);
      g_W16[base + j] =
          __builtin_bit_cast(unsigned short, __float2half(W[k * 128 + col]));
    }
  } else {
    const int c = (g - 112) * 64 + l;
    float v = (c < 128)   ? bgh[c]
              : (c < 256) ? bz[c - 128]
              : (c < 384) ? br[c - 256]
                          : bh[c - 384];
    g_bias[c] = v;
  }
}

// ---------------------------------------------------------------------------
// Kernel 1: MFMA pre-activations. Grid 2048 x 256 thr (4 waves); block does
// 64 rows x 512 cols. Per block:
//  1. stage x_eff / m / dlt as fp16 [64][64] LDS tiles (XOR-swizzled slots)
//  2. each wave rt owns rows rt*16..+15: A-frags -> regs (6 x f16x8)
//  3. per 16-col tile ct (32 of them): load B-frags from g_W16 (L2-hot,
//     coalesced), 2-4 mfma_f32_16x16x32_f16, bias (+ exp(-relu) for gate 0),
//     cvt fp16, scatter into LDS out[64][512] (XOR-swizzled)
//  4. coalesced readback -> A (fp16), layout A[row][4][128] = [G,z,r,h]
// ---------------------------------------------------------------------------
__global__ __launch_bounds__(256) void grud_pre_mfma(
    const float* __restrict__ values, const float* __restrict__ masks,
    const float* __restrict__ deltas, const float* __restrict__ emean,
    const float* __restrict__ locf, const float* __restrict__ w_gamma_x,
    const float* __restrict__ b_gamma_x, __half* __restrict__ A) {
  __shared__ __align__(16) char plds[65536];
  // union layout: tiles xe@0, m@8192, dl@16384 (8KB each);
  // c_wg@24576, c_bg@24832, c_mn@25088 (prologue only);
  // out@0..65535 (epilogue, after tiles are dead)
  float* c_wg = (float*)(plds + 24576);
  float* c_bg = (float*)(plds + 24832);
  float* c_mn = (float*)(plds + 25088);

  const int tid = threadIdx.x;
  const int rowbase = blockIdx.x * 64;

  if (tid < 64) c_wg[tid] = w_gamma_x[tid];
  else if (tid < 128) c_bg[tid - 64] = b_gamma_x[tid - 64];
  else if (tid < 192) c_mn[tid - 128] = emean[tid - 128];
  __syncthreads();

  // ---- prologue: build fp16 tiles ----
  {
    const int r = tid >> 2;        // 0..63
    const int sp = tid & 3;        // slot pair base
    const int swz = (r & 7) << 4;
#pragma unroll
    for (int ss = 0; ss < 2; ++ss) {
      const int s = sp + 4 * ss;   // 16B slot (8 els)
      const int k0 = 8 * s;
      const size_t gb = (size_t)(rowbase + r) * 64 + k0;
      const float4* vp = (const float4*)(values + gb);
      const float4* mp = (const float4*)(masks + gb);
      const float4* dp = (const float4*)(deltas + gb);
      const float4* lp = (const float4*)(locf + gb);
      float4 v0 = vp[0], v1 = vp[1], m0 = mp[0], m1 = mp[1];
      float4 d0 = dp[0], d1 = dp[1], l0 = lp[0], l1 = lp[1];
      float vv[8] = {v0.x, v0.y, v0.z, v0.w, v1.x, v1.y, v1.z, v1.w};
      float mm[8] = {m0.x, m0.y, m0.z, m0.w, m1.x, m1.y, m1.z, m1.w};
      float dd[8] = {d0.x, d0.y, d0.z, d0.w, d1.x, d1.y, d1.z, d1.w};
      float ll[8] = {l0.x, l0.y, l0.z, l0.w, l1.x, l1.y, l1.z, l1.w};
      s16x8 xe_, mv_, dl_;
#pragma unroll
      for (int j = 0; j < 8; ++j) {
        const int d_ = k0 + j;
        float gx = __expf(-fmaxf(c_wg[d_] * dd[j] + c_bg[d_], 0.f));
        float xo = mm[j] * vv[j] +
                   (1.f - mm[j]) * (gx * ll[j] + (1.f - gx) * c_mn[d_]);
        xe_[j] = __builtin_bit_cast(short, __float2half(xo));
        mv_[j] = __builtin_bit_cast(short, __float2half(mm[j]));
        dl_[j] = __builtin_bit_cast(short, __float2half(dd[j]));
      }
      const int ta = r * 128 + ((s * 16) ^ swz);
      *(s16x8*)(plds + ta) = xe_;
      *(s16x8*)(plds + 8192 + ta) = mv_;
      *(s16x8*)(plds + 16384 + ta) = dl_;
    }
  }
  __syncthreads();

  // ---- A-frags to registers ----
  const int l = tid & 63;
  const int rt = tid >> 6;  // wave id = row tile
  f16x8v xe0, xe1, mm0, mm1, dl0, dl1;
  {
    const int r = rt * 16 + (l & 15);
    const int swz = (r & 7) << 4;
    const int s0 = ((l >> 4) * 16) ^ swz;
    const int s1 = (((l >> 4) + 4) * 16) ^ swz;
    xe0 = *(const f16x8v*)(plds + r * 128 + s0);
    xe1 = *(const f16x8v*)(plds + r * 128 + s1);
    mm0 = *(const f16x8v*)(plds + 8192 + r * 128 + s0);
    mm1 = *(const f16x8v*)(plds + 8192 + r * 128 + s1);
    dl0 = *(const f16x8v*)(plds + 16384 + r * 128 + s0);
    dl1 = *(const f16x8v*)(plds + 16384 + r * 128 + s1);
  }
  __syncthreads();  // tiles dead; out region free

  // ---- MFMA + epilogue per col-tile ----
  const s16x8* Wb = (const s16x8*)g_W16;
  const int cc = l & 15;
#pragma unroll 4
  for (int ct = 0; ct < 32; ++ct) {
    const int g = ct >> 3, ctl = ct & 7;
    f32x4 acc = {0.f, 0.f, 0.f, 0.f};
    if (g == 0) {
      s16x8 B0 = Wb[(ctl * 2 + 0) * 64 + l];
      s16x8 B1 = Wb[(ctl * 2 + 1) * 64 + l];
      acc = MFH(dl0, B0, acc);
      acc = MFH(dl1, B1, acc);
    } else {
      const int mx = 2 * g - 1, mmat = 2 * g;
      s16x8 Bx0 = Wb[((mx * 8 + ctl) * 2 + 0) * 64 + l];
      s16x8 Bx1 = Wb[((mx * 8 + ctl) * 2 + 1) * 64 + l];
      s16x8 Bm0 = Wb[((mmat * 8 + ctl) * 2 + 0) * 64 + l];
      s16x8 Bm1 = Wb[((mmat * 8 + ctl) * 2 + 1) * 64 + l];
      acc = MFH(xe0, Bx0, acc);
      acc = MFH(xe1, Bx1, acc);
      acc = MFH(mm0, Bm0, acc);
      acc = MFH(mm1, Bm1, acc);
    }
    const int c = ct * 16 + cc;
    const float bv = g_bias[c];
#pragma unroll
    for (int j = 0; j < 4; ++j) {
      const int row = rt * 16 + (l >> 4) * 4 + j;
      float v = acc[j] + bv;
      if (ct < 8) v = __expf(-fmaxf(v, 0.f));
      *(unsigned short*)(plds + row * 1024 + ((c * 2) ^ ((row & 7) << 4))) =
          __builtin_bit_cast(unsigned short, __float2half(v));
    }
  }
  __syncthreads();

  // ---- coalesced readback + store ----
  {
    const int r = tid >> 2, qq = tid & 3;
    const int swz = (r & 7) << 4;
#pragma unroll
    for (int i = 0; i < 16; ++i) {
      s16x8 v = *(const s16x8*)(plds + r * 1024 + ((qq * 256 + i * 16) ^ swz));
      *(s16x8*)((unsigned short*)A + (size_t)(rowbase + r) * 512 + qq * 128 +
                i * 8) = v;
    }
  }
}

// ---------------------------------------------------------------------------
// Kernel 2: MFMA recurrence (unchanged from round 8; 607us proven).
// 16 blocks x 16 batches, 512 threads (8 waves). Time loop unrolled x4 with
// four NAMED register buffers (static indexing); re-issue depth-4 prefetch;
// lgkm-only barriers; B-fragment LDS layout with bijective scatter.
// ---------------------------------------------------------------------------
#define STEP(T0, CUR, NXT)                                                  \
  do {                                                                      \
    const int t_ = (T0);                                                    \
    h16x4 tAz = CUR[1], tAr = CUR[2], tAh = CUR[3];                         \
    {                                                                       \
      const int t4 = (t_ + 4 < T_) ? t_ + 4 : T_ - 1;                       \
      const size_t r = ((size_t)bg * T_ + t4) * 128 + ci;                   \
      CUR[0] = Arows[r];       CUR[1] = Arows[r + 32];                      \
      CUR[2] = Arows[r + 64];  CUR[3] = Arows[r + 96];                      \
    }                                                                       \
    f32x4 Dz0 = {0,0,0,0}, Dz1 = {0,0,0,0};                                 \
    f32x4 Dr0 = {0,0,0,0}, Dr1 = {0,0,0,0};                                 \
    {                                                                       \
      s16x8 bh0 = *(const s16x8*)(h_bf + off_rd[0]);                        \
      s16x8 bh1 = *(const s16x8*)(h_bf + off_rd[1]);                        \
      s16x8 bh2 = *(const s16x8*)(h_bf + off_rd[2]);                        \
      s16x8 bh3 = *(const s16x8*)(h_bf + off_rd[3]);                        \
      Dz0 = MF(wzf[0], bh0, Dz0); Dr0 = MF(wrf[0], bh0, Dr0);               \
      Dz1 = MF(wzf[2], bh2, Dz1); Dr1 = MF(wrf[2], bh2, Dr1);               \
      Dz0 = MF(wzf[1], bh1, Dz0); Dr0 = MF(wrf[1], bh1, Dr0);               \
      Dz1 = MF(wzf[3], bh3, Dz1); Dr1 = MF(wrf[3], bh3, Dr1);               \
    }                                                                       \
    f32x4 zz;                                                               \
    s16x4 rhv;                                                              \
    _Pragma("unroll")                                                       \
    for (int j = 0; j < 4; ++j) {                                           \
      zz[j] = fsig((float)tAz[j] + (Dz0[j] + Dz1[j]));                      \
      float rr = fsig((float)tAr[j] + (Dr0[j] + Dr1[j]));                   \
      rhv[j] = f2bf(rr * hsc[j]);                                           \
    }                                                                       \
    *(s16x4*)(rh_bf + off_wr) = rhv;                                        \
    BAR();                                                                  \
    f32x4 Dh0 = {0,0,0,0}, Dh1 = {0,0,0,0};                                 \
    {                                                                       \
      s16x8 p0 = *(const s16x8*)(rh_bf + off_rd[0]);                        \
      s16x8 p1 = *(const s16x8*)(rh_bf + off_rd[1]);                        \
      s16x8 p2 = *(const s16x8*)(rh_bf + off_rd[2]);                        \
      s16x8 p3 = *(const s16x8*)(rh_bf + off_rd[3]);                        \
      Dh0 = MF(whf[0], p0, Dh0); Dh1 = MF(whf[2], p2, Dh1);                 \
      Dh0 = MF(whf[1], p1, Dh0); Dh1 = MF(whf[3], p3, Dh1);                 \
    }                                                                       \
    f32x4 hnv;                                                              \
    s16x4 hbv;                                                              \
    _Pragma("unroll")                                                       \
    for (int j = 0; j < 4; ++j) {                                           \
      float ht = ftanh((float)tAh[j] + (Dh0[j] + Dh1[j]));                  \
      float hn = (1.f - zz[j]) * hsc[j] + zz[j] * ht;                       \
      hnv[j] = hn;                                                          \
      float hg = hn * (float)NXT[0][j];                                     \
      hsc[j] = hg;                                                          \
      hbv[j] = f2bf(hg);                                                    \
    }                                                                       \
    *(f32x4*)(hid + ((size_t)bg * T_ + t_) * H_ + cb) = hnv;                \
    if (t_ == T_ - 1) *(f32x4*)(hlast + (size_t)bg * H_ + cb) = hnv;        \
    *(s16x4*)(h_bf + off_wr) = hbv;                                         \
    BAR();                                                                  \
  } while (0)

__global__ __launch_bounds__(512, 1) void grud_rec_mfma(
    const __half* __restrict__ A, const float* __restrict__ w_zh,
    const float* __restrict__ w_rh, const float* __restrict__ w_hh,
    float* __restrict__ hid, float* __restrict__ hlast) {
  const int tid = threadIdx.x;
  const int w = tid >> 6;
  const int lane = tid & 63;
  const int b = lane & 15;
  const int q = lane >> 4;
  const int cb = w * 16 + q * 4;
  const int bg = blockIdx.x * BB + b;

  __shared__ __align__(16) char lds[8192];
  char* h_bf = lds;
  char* rh_bf = lds + 4096;

  s16x8 wzf[4], wrf[4], whf[4];
#pragma unroll
  for (int tau = 0; tau < 4; ++tau) {
    s16x8 az, ar, ah;
#pragma unroll
    for (int j = 0; j < 8; ++j) {
      const int k = q * 8 + j + 32 * tau;
      az[j] = f2bf(w_zh[k * H_ + w * 16 + b]);
      ar[j] = f2bf(w_rh[k * H_ + w * 16 + b]);
      ah[j] = f2bf(w_hh[k * H_ + w * 16 + b]);
    }
    wzf[tau] = az; wrf[tau] = ar; whf[tau] = ah;
  }

  for (int i = tid; i < 8192 / 16; i += 512)
    ((f32x4*)lds)[i] = f32x4{0.f, 0.f, 0.f, 0.f};

  int off_rd[4];
#pragma unroll
  for (int tau = 0; tau < 4; ++tau) off_rd[tau] = tau * 1024 + lane * 16;
  const int off_wr =
      (w >> 1) * 1024 + (b + 16 * ((2 * w + (q >> 1)) & 3)) * 16 + 8 * (q & 1);

  const h16x4* Arows = (const h16x4*)A;
  const int ci = cb >> 2;

  h16x4 b0[4], b1[4], b2[4], b3[4];
  {
    const size_t r0 = ((size_t)bg * T_ + 0) * 128 + ci;
    b0[0] = Arows[r0]; b0[1] = Arows[r0 + 32];
    b0[2] = Arows[r0 + 64]; b0[3] = Arows[r0 + 96];
    const size_t r1 = ((size_t)bg * T_ + 1) * 128 + ci;
    b1[0] = Arows[r1]; b1[1] = Arows[r1 + 32];
    b1[2] = Arows[r1 + 64]; b1[3] = Arows[r1 + 96];
    const size_t r2 = ((size_t)bg * T_ + 2) * 128 + ci;
    b2[0] = Arows[r2]; b2[1] = Arows[r2 + 32];
    b2[2] = Arows[r2 + 64]; b2[3] = Arows[r2 + 96];
    const size_t r3 = ((size_t)bg * T_ + 3) * 128 + ci;
    b3[0] = Arows[r3]; b3[1] = Arows[r3 + 32];
    b3[2] = Arows[r3 + 64]; b3[3] = Arows[r3 + 96];
  }
  f32x4 hsc = {0.f, 0.f, 0.f, 0.f};
  __syncthreads();

  for (int tp = 0; tp < T_; tp += 4) {
    STEP(tp + 0, b0, b1);
    STEP(tp + 1, b1, b2);
    STEP(tp + 2, b2, b3);
    STEP(tp + 3, b3, b0);
  }
}

extern "C" void kernel_launch(void* const* d_in, const int* in_sizes, int n_in,
                              void* d_out, int out_size, void* d_ws, size_t ws_size,
                              hipStream_t stream) {
  const float* values = (const float*)d_in[0];
  const float* masks = (const float*)d_in[1];
  const float* deltas = (const float*)d_in[2];
  const float* emean = (const float*)d_in[3];
  const float* locf = (const float*)d_in[4];
  const float* w_gamma_x = (const float*)d_in[5];
  const float* w_gamma_h = (const float*)d_in[6];
  const float* w_rx = (const float*)d_in[7];
  const float* w_rh = (const float*)d_in[8];
  const float* w_rm = (const float*)d_in[9];
  const float* w_zx = (const float*)d_in[10];
  const float* w_zh = (const float*)d_in[11];
  const float* w_zm = (const float*)d_in[12];
  const float* w_hx = (const float*)d_in[13];
  const float* w_hh = (const float*)d_in[14];
  const float* w_hm = (const float*)d_in[15];
  const float* b_gamma_x = (const float*)d_in[16];
  const float* b_gamma_h = (const float*)d_in[17];
  const float* b_r = (const float*)d_in[18];
  const float* b_z = (const float*)d_in[19];
  const float* b_h = (const float*)d_in[20];

  float* hid = (float*)d_out;
  float* hlast = hid + (size_t)B_ * T_ * H_;
  __half* A = (__half*)d_ws;

  wprep<<<dim3(120), dim3(64), 0, stream>>>(
      w_gamma_h, w_zx, w_zm, w_rx, w_rm, w_hx, w_hm, b_gamma_h, b_z, b_r, b_h);
  grud_pre_mfma<<<dim3(B_ * T_ / 64), dim3(256), 0, stream>>>(
      values, masks, deltas, emean, locf, w_gamma_x, b_gamma_x, A);
  grud_rec_mfma<<<dim3(B_ / BB), dim3(512), 0, stream>>>(A, w_zh, w_rh, w_hh,
                                                         hid, hlast);
}

// Round 10
// 730.775 us; speedup vs baseline: 1.7575x; 1.0336x over previous
//
#include <hip/hip_runtime.h>
#include <hip/hip_fp16.h>

#define B_ 256
#define T_ 512
#define D_ 64
#define H_ 128
#define BB 16  // batches per recurrent block

typedef float f32x4 __attribute__((ext_vector_type(4)));
typedef short s16x4 __attribute__((ext_vector_type(4)));
typedef short s16x8 __attribute__((ext_vector_type(8)));
typedef __bf16 bf16x8 __attribute__((ext_vector_type(8)));
typedef _Float16 h16x4 __attribute__((ext_vector_type(4)));
typedef _Float16 f16x8v __attribute__((ext_vector_type(8)));

__device__ unsigned short g_W16[7 * 8 * 2 * 512];  // fp16 frag-ordered weights
__device__ float g_bias[512];                      // [G,z,r,h] biases

__device__ inline float fsig(float x) {
  return __builtin_amdgcn_rcpf(1.f + __expf(-x));
}
__device__ inline float ftanh(float x) {
  return 1.f - 2.f * __builtin_amdgcn_rcpf(1.f + __expf(2.f * x));
}
__device__ inline short f2bf(float f) {  // RNE float->bf16
  unsigned u = __builtin_bit_cast(unsigned, f);
  u += 0x7fff + ((u >> 16) & 1);
  return (short)(u >> 16);
}
__device__ __forceinline__ f32x4 MF(s16x8 a, s16x8 b, f32x4 c) {
  return __builtin_amdgcn_mfma_f32_16x16x32_bf16(
      __builtin_bit_cast(bf16x8, a), __builtin_bit_cast(bf16x8, b), c, 0, 0, 0);
}
// weights-as-A fp16 MFMA: D^T = W^T-slice * X-frag
__device__ __forceinline__ f32x4 MFH2(s16x8 wfrag, f16x8v xfrag, f32x4 c) {
  return __builtin_amdgcn_mfma_f32_16x16x32_f16(
      __builtin_bit_cast(f16x8v, wfrag), xfrag, c, 0, 0, 0);
}

// Barrier draining ONLY LDS ops: global loads/stores stay in flight.
#define BAR()                                              \
  do {                                                     \
    asm volatile("s_waitcnt lgkmcnt(0)" ::: "memory");     \
    __builtin_amdgcn_s_barrier();                          \
  } while (0)

// ---------------------------------------------------------------------------
// Kernel 0: weight prep (unchanged). g_W16 frag layout per (mat, ct, tau):
// value = W[k=8*(l>>4)+j+32*tau][col=ct*16+(l&15)] — serves as the A-operand
// (W^T slice) in the swapped-operand pre MFMA.
// ---------------------------------------------------------------------------
__global__ __launch_bounds__(64) void wprep(
    const float* __restrict__ wgh, const float* __restrict__ wzx,
    const float* __restrict__ wzm, const float* __restrict__ wrx,
    const float* __restrict__ wrm, const float* __restrict__ whx,
    const float* __restrict__ whm, const float* __restrict__ bgh,
    const float* __restrict__ bz, const float* __restrict__ br,
    const float* __restrict__ bh) {
  const int g = blockIdx.x, l = threadIdx.x;
  if (g < 112) {
    const float* mats[7] = {wgh, wzx, wzm, wrx, wrm, whx, whm};
    const int mat = g >> 4, sub = g & 15, ct = sub >> 1, tau = sub & 1;
    const float* W = mats[mat];
    const int base = ((mat * 8 + ct) * 2 + tau) * 512 + l * 8;
#pragma unroll
    for (int j = 0; j < 8; ++j) {
      const int k = 8 * (l >> 4) + j + 32 * tau;
      const int col = ct * 16 + (l & 15);
      g_W16[base + j] =
          __builtin_bit_cast(unsigned short, __float2half(W[k * 128 + col]));
    }
  } else {
    const int c = (g - 112) * 64 + l;
    float v = (c < 128)   ? bgh[c]
              : (c < 256) ? bz[c - 128]
              : (c < 384) ? br[c - 256]
                          : bh[c - 384];
    g_bias[c] = v;
  }
}

// ---------------------------------------------------------------------------
// Kernel 1: MFMA pre-activations, swapped operands (A=W^T, B=X-frags).
// D layout then gives each lane 4 CONSECUTIVE output cols for one row ->
// direct 8B global store per col-tile; no LDS bounce / readback at all.
// A layout: [row=b*T+t][4 gates][128] fp16, gate order [G,z,r,h], G pre-exp'd.
// ---------------------------------------------------------------------------
__global__ __launch_bounds__(256) void grud_pre_mfma(
    const float* __restrict__ values, const float* __restrict__ masks,
    const float* __restrict__ deltas, const float* __restrict__ emean,
    const float* __restrict__ locf, const float* __restrict__ w_gamma_x,
    const float* __restrict__ b_gamma_x, __half* __restrict__ A) {
  __shared__ __align__(16) char plds[25344];
  // tiles: xe@0, m@8192, dl@16384 (8KB each); consts @24576+
  float* c_wg = (float*)(plds + 24576);
  float* c_bg = (float*)(plds + 24832);
  float* c_mn = (float*)(plds + 25088);

  const int tid = threadIdx.x;
  const int rowbase = blockIdx.x * 64;

  if (tid < 64) c_wg[tid] = w_gamma_x[tid];
  else if (tid < 128) c_bg[tid - 64] = b_gamma_x[tid - 64];
  else if (tid < 192) c_mn[tid - 128] = emean[tid - 128];
  __syncthreads();

  // ---- prologue: build fp16 tiles (XOR-swizzled 16B slots) ----
  {
    const int r = tid >> 2;
    const int sp = tid & 3;
    const int swz = (r & 7) << 4;
#pragma unroll
    for (int ss = 0; ss < 2; ++ss) {
      const int s = sp + 4 * ss;
      const int k0 = 8 * s;
      const size_t gb = (size_t)(rowbase + r) * 64 + k0;
      const float4* vp = (const float4*)(values + gb);
      const float4* mp = (const float4*)(masks + gb);
      const float4* dp = (const float4*)(deltas + gb);
      const float4* lp = (const float4*)(locf + gb);
      float4 v0 = vp[0], v1 = vp[1], m0 = mp[0], m1 = mp[1];
      float4 d0 = dp[0], d1 = dp[1], l0 = lp[0], l1 = lp[1];
      float vv[8] = {v0.x, v0.y, v0.z, v0.w, v1.x, v1.y, v1.z, v1.w};
      float mm[8] = {m0.x, m0.y, m0.z, m0.w, m1.x, m1.y, m1.z, m1.w};
      float dd[8] = {d0.x, d0.y, d0.z, d0.w, d1.x, d1.y, d1.z, d1.w};
      float ll[8] = {l0.x, l0.y, l0.z, l0.w, l1.x, l1.y, l1.z, l1.w};
      s16x8 xe_, mv_, dl_;
#pragma unroll
      for (int j = 0; j < 8; ++j) {
        const int d_ = k0 + j;
        float gx = __expf(-fmaxf(c_wg[d_] * dd[j] + c_bg[d_], 0.f));
        float xo = mm[j] * vv[j] +
                   (1.f - mm[j]) * (gx * ll[j] + (1.f - gx) * c_mn[d_]);
        xe_[j] = __builtin_bit_cast(short, __float2half(xo));
        mv_[j] = __builtin_bit_cast(short, __float2half(mm[j]));
        dl_[j] = __builtin_bit_cast(short, __float2half(dd[j]));
      }
      const int ta = r * 128 + ((s * 16) ^ swz);
      *(s16x8*)(plds + ta) = xe_;
      *(s16x8*)(plds + 8192 + ta) = mv_;
      *(s16x8*)(plds + 16384 + ta) = dl_;
    }
  }
  __syncthreads();

  // ---- X B-frags to registers: B[k][col=r] for rows r=rt*16+(l&15) ----
  const int l = tid & 63;
  const int rt = tid >> 6;  // wave id = row tile
  f16x8v xe0, xe1, mm0, mm1, dl0, dl1;
  {
    const int r = rt * 16 + (l & 15);
    const int swz = (r & 7) << 4;
    const int s0 = ((l >> 4) * 16) ^ swz;
    const int s1 = (((l >> 4) + 4) * 16) ^ swz;
    xe0 = *(const f16x8v*)(plds + r * 128 + s0);
    xe1 = *(const f16x8v*)(plds + r * 128 + s1);
    mm0 = *(const f16x8v*)(plds + 8192 + r * 128 + s0);
    mm1 = *(const f16x8v*)(plds + 8192 + r * 128 + s1);
    dl0 = *(const f16x8v*)(plds + 16384 + r * 128 + s0);
    dl1 = *(const f16x8v*)(plds + 16384 + r * 128 + s1);
  }

  // ---- MFMA + direct-store epilogue per 16-col tile ----
  const s16x8* Wb = (const s16x8*)g_W16;
  const int cj = (l >> 4) * 4;  // lane's 4-col base within tile
  const int row = rowbase + rt * 16 + (l & 15);
  unsigned short* Aout = (unsigned short*)A + (size_t)row * 512;
#pragma unroll 4
  for (int ct = 0; ct < 32; ++ct) {
    const int g = ct >> 3, ctl = ct & 7;
    f32x4 acc = {0.f, 0.f, 0.f, 0.f};
    if (g == 0) {
      s16x8 B0 = Wb[(ctl * 2 + 0) * 64 + l];
      s16x8 B1 = Wb[(ctl * 2 + 1) * 64 + l];
      acc = MFH2(B0, dl0, acc);
      acc = MFH2(B1, dl1, acc);
    } else {
      const int mx = 2 * g - 1, mmat = 2 * g;
      s16x8 Bx0 = Wb[((mx * 8 + ctl) * 2 + 0) * 64 + l];
      s16x8 Bx1 = Wb[((mx * 8 + ctl) * 2 + 1) * 64 + l];
      s16x8 Bm0 = Wb[((mmat * 8 + ctl) * 2 + 0) * 64 + l];
      s16x8 Bm1 = Wb[((mmat * 8 + ctl) * 2 + 1) * 64 + l];
      acc = MFH2(Bx0, xe0, acc);
      acc = MFH2(Bx1, xe1, acc);
      acc = MFH2(Bm0, mm0, acc);
      acc = MFH2(Bm1, mm1, acc);
    }
    const f32x4 bv = *(const f32x4*)(g_bias + ct * 16 + cj);
    h16x4 outv;
#pragma unroll
    for (int j = 0; j < 4; ++j) {
      float v = acc[j] + bv[j];
      if (ct < 8) v = __expf(-fmaxf(v, 0.f));
      outv[j] = (_Float16)v;
    }
    *(h16x4*)(Aout + g * 128 + ctl * 16 + cj) = outv;
  }
}

// ---------------------------------------------------------------------------
// Kernel 2: MFMA recurrence, 4 waves x 32 cols (256 threads), 16 blocks.
// Halves LDS B-frag traffic vs 8-wave config (reads shared across the two
// col-tiles AND z/r). Wave w owns cols [w*32, w*32+32): tiles A (s=0) and
// B (s=1). h/rh in LDS in B-fragment order: read tau*1024 + lane*16 (linear,
// conflict-free); scatter write (bijective): (w,b,q,s) ->
//   w*1024 + (s*2+(q>>1))*256 + b*16 + (q&1)*8.
// Named 4-deep prefetch buffers; lgkm-only barriers; h state in registers.
// ---------------------------------------------------------------------------
#define STEP(T0, CUR, NXT)                                                  \
  do {                                                                      \
    const int t_ = (T0);                                                    \
    h16x4 tAz0 = CUR[2], tAz1 = CUR[3], tAr0 = CUR[4], tAr1 = CUR[5];       \
    h16x4 tAh0 = CUR[6], tAh1 = CUR[7];                                     \
    { /* re-issue CUR <- rows t+4 */                                        \
      const int t4 = (t_ + 4 < T_) ? t_ + 4 : T_ - 1;                       \
      const size_t r = ((size_t)bg * T_ + t4) * 128;                        \
      CUR[0] = Arows[r + ciA];      CUR[1] = Arows[r + ciB];                \
      CUR[2] = Arows[r + 32 + ciA]; CUR[3] = Arows[r + 32 + ciB];           \
      CUR[4] = Arows[r + 64 + ciA]; CUR[5] = Arows[r + 64 + ciB];           \
      CUR[6] = Arows[r + 96 + ciA]; CUR[7] = Arows[r + 96 + ciB];           \
    }                                                                       \
    f32x4 DzA0 = {0,0,0,0}, DzA1 = {0,0,0,0};                               \
    f32x4 DzB0 = {0,0,0,0}, DzB1 = {0,0,0,0};                               \
    f32x4 DrA0 = {0,0,0,0}, DrA1 = {0,0,0,0};                               \
    f32x4 DrB0 = {0,0,0,0}, DrB1 = {0,0,0,0};                               \
    {                                                                       \
      s16x8 bh0 = *(const s16x8*)(h_bf + off_rd[0]);                        \
      s16x8 bh1 = *(const s16x8*)(h_bf + off_rd[1]);                        \
      s16x8 bh2 = *(const s16x8*)(h_bf + off_rd[2]);                        \
      s16x8 bh3 = *(const s16x8*)(h_bf + off_rd[3]);                        \
      DzA0 = MF(wzf0[0], bh0, DzA0); DzB0 = MF(wzf1[0], bh0, DzB0);         \
      DrA0 = MF(wrf0[0], bh0, DrA0); DrB0 = MF(wrf1[0], bh0, DrB0);         \
      DzA1 = MF(wzf0[2], bh2, DzA1); DzB1 = MF(wzf1[2], bh2, DzB1);         \
      DrA1 = MF(wrf0[2], bh2, DrA1); DrB1 = MF(wrf1[2], bh2, DrB1);         \
      DzA0 = MF(wzf0[1], bh1, DzA0); DzB0 = MF(wzf1[1], bh1, DzB0);         \
      DrA0 = MF(wrf0[1], bh1, DrA0); DrB0 = MF(wrf1[1], bh1, DrB0);         \
      DzA1 = MF(wzf0[3], bh3, DzA1); DzB1 = MF(wzf1[3], bh3, DzB1);         \
      DrA1 = MF(wrf0[3], bh3, DrA1); DrB1 = MF(wrf1[3], bh3, DrB1);         \
    }                                                                       \
    f32x4 zzA, zzB;                                                         \
    s16x4 rhvA, rhvB;                                                       \
    _Pragma("unroll")                                                       \
    for (int j = 0; j < 4; ++j) {                                           \
      zzA[j] = fsig((float)tAz0[j] + (DzA0[j] + DzA1[j]));                  \
      float rA = fsig((float)tAr0[j] + (DrA0[j] + DrA1[j]));                \
      rhvA[j] = f2bf(rA * hscA[j]);                                         \
      zzB[j] = fsig((float)tAz1[j] + (DzB0[j] + DzB1[j]));                  \
      float rB = fsig((float)tAr1[j] + (DrB0[j] + DrB1[j]));                \
      rhvB[j] = f2bf(rB * hscB[j]);                                         \
    }                                                                       \
    *(s16x4*)(rh_bf + off_wrA) = rhvA;                                      \
    *(s16x4*)(rh_bf + off_wrB) = rhvB;                                      \
    BAR();                                                                  \
    f32x4 DhA0 = {0,0,0,0}, DhA1 = {0,0,0,0};                               \
    f32x4 DhB0 = {0,0,0,0}, DhB1 = {0,0,0,0};                               \
    {                                                                       \
      s16x8 p0 = *(const s16x8*)(rh_bf + off_rd[0]);                        \
      s16x8 p1 = *(const s16x8*)(rh_bf + off_rd[1]);                        \
      s16x8 p2 = *(const s16x8*)(rh_bf + off_rd[2]);                        \
      s16x8 p3 = *(const s16x8*)(rh_bf + off_rd[3]);                        \
      DhA0 = MF(whf0[0], p0, DhA0); DhB0 = MF(whf1[0], p0, DhB0);           \
      DhA1 = MF(whf0[2], p2, DhA1); DhB1 = MF(whf1[2], p2, DhB1);           \
      DhA0 = MF(whf0[1], p1, DhA0); DhB0 = MF(whf1[1], p1, DhB0);           \
      DhA1 = MF(whf0[3], p3, DhA1); DhB1 = MF(whf1[3], p3, DhB1);           \
    }                                                                       \
    f32x4 hnA, hnB;                                                         \
    s16x4 hbvA, hbvB;                                                       \
    _Pragma("unroll")                                                       \
    for (int j = 0; j < 4; ++j) {                                           \
      float htA = ftanh((float)tAh0[j] + (DhA0[j] + DhA1[j]));              \
      float ha = hscA[j] + zzA[j] * (htA - hscA[j]);                        \
      hnA[j] = ha;                                                          \
      float hgA = ha * (float)NXT[0][j];                                    \
      hscA[j] = hgA; hbvA[j] = f2bf(hgA);                                   \
      float htB = ftanh((float)tAh1[j] + (DhB0[j] + DhB1[j]));              \
      float hb = hscB[j] + zzB[j] * (htB - hscB[j]);                        \
      hnB[j] = hb;                                                          \
      float hgB = hb * (float)NXT[1][j];                                    \
      hscB[j] = hgB; hbvB[j] = f2bf(hgB);                                   \
    }                                                                       \
    *(f32x4*)(hid + ((size_t)bg * T_ + t_) * H_ + cbA) = hnA;               \
    *(f32x4*)(hid + ((size_t)bg * T_ + t_) * H_ + cbB) = hnB;               \
    if (t_ == T_ - 1) {                                                     \
      *(f32x4*)(hlast + (size_t)bg * H_ + cbA) = hnA;                       \
      *(f32x4*)(hlast + (size_t)bg * H_ + cbB) = hnB;                       \
    }                                                                       \
    *(s16x4*)(h_bf + off_wrA) = hbvA;                                       \
    *(s16x4*)(h_bf + off_wrB) = hbvB;                                       \
    BAR();                                                                  \
  } while (0)

__global__ __launch_bounds__(256, 1) void grud_rec_mfma(
    const __half* __restrict__ A, const float* __restrict__ w_zh,
    const float* __restrict__ w_rh, const float* __restrict__ w_hh,
    float* __restrict__ hid, float* __restrict__ hlast) {
  const int tid = threadIdx.x;
  const int w = tid >> 6;
  const int l = tid & 63;
  const int b = l & 15;
  const int q = l >> 4;
  const int cbA = w * 32 + q * 4;
  const int cbB = cbA + 16;
  const int bg = blockIdx.x * BB + b;

  __shared__ __align__(16) char lds[8192];
  char* h_bf = lds;
  char* rh_bf = lds + 4096;

  // A-frags for both col-tiles: wXf{0,1}[tau][j] = W[q*8+j+32tau][w*32+s*16+b]
  s16x8 wzf0[4], wzf1[4], wrf0[4], wrf1[4], whf0[4], whf1[4];
#pragma unroll
  for (int tau = 0; tau < 4; ++tau) {
    s16x8 z0, z1, r0v, r1v, h0v, h1v;
#pragma unroll
    for (int j = 0; j < 8; ++j) {
      const int k = q * 8 + j + 32 * tau;
      const int n0 = w * 32 + b;
      const int n1 = n0 + 16;
      z0[j] = f2bf(w_zh[k * H_ + n0]); z1[j] = f2bf(w_zh[k * H_ + n1]);
      r0v[j] = f2bf(w_rh[k * H_ + n0]); r1v[j] = f2bf(w_rh[k * H_ + n1]);
      h0v[j] = f2bf(w_hh[k * H_ + n0]); h1v[j] = f2bf(w_hh[k * H_ + n1]);
    }
    wzf0[tau] = z0; wzf1[tau] = z1;
    wrf0[tau] = r0v; wrf1[tau] = r1v;
    whf0[tau] = h0v; whf1[tau] = h1v;
  }

  for (int i = tid; i < 8192 / 16; i += 256)
    ((f32x4*)lds)[i] = f32x4{0.f, 0.f, 0.f, 0.f};

  int off_rd[4];
#pragma unroll
  for (int tau = 0; tau < 4; ++tau) off_rd[tau] = tau * 1024 + l * 16;
  const int off_wrA = w * 1024 + (q >> 1) * 256 + b * 16 + (q & 1) * 8;
  const int off_wrB = off_wrA + 512;

  const h16x4* Arows = (const h16x4*)A;
  const int ciA = w * 8 + q;   // = cbA>>2
  const int ciB = ciA + 4;

  // 4 named prefetch buffers, each [G0,G1,z0,z1,r0,r1,h0,h1]
  h16x4 b0[8], b1[8], b2[8], b3[8];
#pragma unroll
  for (int t0 = 0; t0 < 4; ++t0) {
    h16x4* dst = (t0 == 0) ? b0 : (t0 == 1) ? b1 : (t0 == 2) ? b2 : b3;
    const size_t r = ((size_t)bg * T_ + t0) * 128;
    dst[0] = Arows[r + ciA];      dst[1] = Arows[r + ciB];
    dst[2] = Arows[r + 32 + ciA]; dst[3] = Arows[r + 32 + ciB];
    dst[4] = Arows[r + 64 + ciA]; dst[5] = Arows[r + 64 + ciB];
    dst[6] = Arows[r + 96 + ciA]; dst[7] = Arows[r + 96 + ciB];
  }
  f32x4 hscA = {0.f, 0.f, 0.f, 0.f}, hscB = {0.f, 0.f, 0.f, 0.f};
  __syncthreads();

  for (int tp = 0; tp < T_; tp += 4) {
    STEP(tp + 0, b0, b1);
    STEP(tp + 1, b1, b2);
    STEP(tp + 2, b2, b3);
    STEP(tp + 3, b3, b0);
  }
}

extern "C" void kernel_launch(void* const* d_in, const int* in_sizes, int n_in,
                              void* d_out, int out_size, void* d_ws, size_t ws_size,
                              hipStream_t stream) {
  const float* values = (const float*)d_in[0];
  const float* masks = (const float*)d_in[1];
  const float* deltas = (const float*)d_in[2];
  const float* emean = (const float*)d_in[3];
  const float* locf = (const float*)d_in[4];
  const float* w_gamma_x = (const float*)d_in[5];
  const float* w_gamma_h = (const float*)d_in[6];
  const float* w_rx = (const float*)d_in[7];
  const float* w_rh = (const float*)d_in[8];
  const float* w_rm = (const float*)d_in[9];
  const float* w_zx = (const float*)d_in[10];
  const float* w_zh = (const float*)d_in[11];
  const float* w_zm = (const float*)d_in[12];
  const float* w_hx = (const float*)d_in[13];
  const float* w_hh = (const float*)d_in[14];
  const float* w_hm = (const float*)d_in[15];
  const float* b_gamma_x = (const float*)d_in[16];
  const float* b_gamma_h = (const float*)d_in[17];
  const float* b_r = (const float*)d_in[18];
  const float* b_z = (const float*)d_in[19];
  const float* b_h = (const float*)d_in[20];

  float* hid = (float*)d_out;
  float* hlast = hid + (size_t)B_ * T_ * H_;
  __half* A = (__half*)d_ws;

  wprep<<<dim3(120), dim3(64), 0, stream>>>(
      w_gamma_h, w_zx, w_zm, w_rx, w_rm, w_hx, w_hm, b_gamma_h, b_z, b_r, b_h);
  grud_pre_mfma<<<dim3(B_ * T_ / 64), dim3(256), 0, stream>>>(
      values, masks, deltas, emean, locf, w_gamma_x, b_gamma_x, A);
  grud_rec_mfma<<<dim3(B_ / BB), dim3(256), 0, stream>>>(A, w_zh, w_rh, w_hh,
                                                         hid, hlast);
}

// Round 12
// 630.997 us; speedup vs baseline: 2.0354x; 1.1581x over previous
//
#include <hip/hip_runtime.h>
#include <hip/hip_fp16.h>

#define B_ 256
#define T_ 512
#define D_ 64
#define H_ 128
#define BB 16  // batches per recurrent block

typedef float f32x4 __attribute__((ext_vector_type(4)));
typedef short s16x4 __attribute__((ext_vector_type(4)));
typedef short s16x8 __attribute__((ext_vector_type(8)));
typedef __fp16 fp16x2 __attribute__((ext_vector_type(2)));
typedef _Float16 h16x4 __attribute__((ext_vector_type(4)));
typedef _Float16 f16x8v __attribute__((ext_vector_type(8)));

__device__ unsigned short g_W16[7 * 8 * 2 * 512];  // fp16 frag-ordered weights
__device__ float g_bias[512];                      // [G,z,r,h] biases

__device__ inline float fsig(float x) {
  return __builtin_amdgcn_rcpf(1.f + __expf(-x));
}
__device__ inline float ftanh(float x) {
  return 1.f - 2.f * __builtin_amdgcn_rcpf(1.f + __expf(2.f * x));
}
// fp16 MFMA, both operands as raw 16-bit fragments
__device__ __forceinline__ f32x4 MFH(s16x8 a, s16x8 b, f32x4 c) {
  return __builtin_amdgcn_mfma_f32_16x16x32_f16(
      __builtin_bit_cast(f16x8v, a), __builtin_bit_cast(f16x8v, b), c, 0, 0, 0);
}
__device__ __forceinline__ f32x4 MFH2(s16x8 wfrag, f16x8v xfrag, f32x4 c) {
  return __builtin_amdgcn_mfma_f32_16x16x32_f16(
      __builtin_bit_cast(f16x8v, wfrag), xfrag, c, 0, 0, 0);
}

// Barrier draining ONLY LDS ops: global loads/stores stay in flight.
#define BAR()                                              \
  do {                                                     \
    asm volatile("s_waitcnt lgkmcnt(0)" ::: "memory");     \
    __builtin_amdgcn_s_barrier();                          \
  } while (0)

// ---------------------------------------------------------------------------
// Kernel 0: weight prep (unchanged). g_W16 frag layout per (mat, ct, tau):
// value = W[k=8*(l>>4)+j+32*tau][col=ct*16+(l&15)].
// ---------------------------------------------------------------------------
__global__ __launch_bounds__(64) void wprep(
    const float* __restrict__ wgh, const float* __restrict__ wzx,
    const float* __restrict__ wzm, const float* __restrict__ wrx,
    const float* __restrict__ wrm, const float* __restrict__ whx,
    const float* __restrict__ whm, const float* __restrict__ bgh,
    const float* __restrict__ bz, const float* __restrict__ br,
    const float* __restrict__ bh) {
  const int g = blockIdx.x, l = threadIdx.x;
  if (g < 112) {
    const float* mats[7] = {wgh, wzx, wzm, wrx, wrm, whx, whm};
    const int mat = g >> 4, sub = g & 15, ct = sub >> 1, tau = sub & 1;
    const float* W = mats[mat];
    const int base = ((mat * 8 + ct) * 2 + tau) * 512 + l * 8;
#pragma unroll
    for (int j = 0; j < 8; ++j) {
      const int k = 8 * (l >> 4) + j + 32 * tau;
      const int col = ct * 16 + (l & 15);
      g_W16[base + j] =
          __builtin_bit_cast(unsigned short, __float2half(W[k * 128 + col]));
    }
  } else {
    const int c = (g - 112) * 64 + l;
    float v = (c < 128)   ? bgh[c]
              : (c < 256) ? bz[c - 128]
              : (c < 384) ? br[c - 256]
                          : bh[c - 384];
    g_bias[c] = v;
  }
}

// ---------------------------------------------------------------------------
// Kernel 1 (unchanged from r10): MFMA pre-activations, swapped operands
// (A=W^T, B=X-frags), direct 8B stores. A layout [row][4 gates][128] fp16,
// gate order [G,z,r,h], G pre-exponentiated.
// ---------------------------------------------------------------------------
__global__ __launch_bounds__(256) void grud_pre_mfma(
    const float* __restrict__ values, const float* __restrict__ masks,
    const float* __restrict__ deltas, const float* __restrict__ emean,
    const float* __restrict__ locf, const float* __restrict__ w_gamma_x,
    const float* __restrict__ b_gamma_x, __half* __restrict__ A) {
  __shared__ __align__(16) char plds[25344];
  float* c_wg = (float*)(plds + 24576);
  float* c_bg = (float*)(plds + 24832);
  float* c_mn = (float*)(plds + 25088);

  const int tid = threadIdx.x;
  const int rowbase = blockIdx.x * 64;

  if (tid < 64) c_wg[tid] = w_gamma_x[tid];
  else if (tid < 128) c_bg[tid - 64] = b_gamma_x[tid - 64];
  else if (tid < 192) c_mn[tid - 128] = emean[tid - 128];
  __syncthreads();

  {
    const int r = tid >> 2;
    const int sp = tid & 3;
    const int swz = (r & 7) << 4;
#pragma unroll
    for (int ss = 0; ss < 2; ++ss) {
      const int s = sp + 4 * ss;
      const int k0 = 8 * s;
      const size_t gb = (size_t)(rowbase + r) * 64 + k0;
      const float4* vp = (const float4*)(values + gb);
      const float4* mp = (const float4*)(masks + gb);
      const float4* dp = (const float4*)(deltas + gb);
      const float4* lp = (const float4*)(locf + gb);
      float4 v0 = vp[0], v1 = vp[1], m0 = mp[0], m1 = mp[1];
      float4 d0 = dp[0], d1 = dp[1], l0 = lp[0], l1 = lp[1];
      float vv[8] = {v0.x, v0.y, v0.z, v0.w, v1.x, v1.y, v1.z, v1.w};
      float mm[8] = {m0.x, m0.y, m0.z, m0.w, m1.x, m1.y, m1.z, m1.w};
      float dd[8] = {d0.x, d0.y, d0.z, d0.w, d1.x, d1.y, d1.z, d1.w};
      float ll[8] = {l0.x, l0.y, l0.z, l0.w, l1.x, l1.y, l1.z, l1.w};
      s16x8 xe_, mv_, dl_;
#pragma unroll
      for (int j = 0; j < 8; ++j) {
        const int d_ = k0 + j;
        float gx = __expf(-fmaxf(c_wg[d_] * dd[j] + c_bg[d_], 0.f));
        float xo = mm[j] * vv[j] +
                   (1.f - mm[j]) * (gx * ll[j] + (1.f - gx) * c_mn[d_]);
        xe_[j] = __builtin_bit_cast(short, __float2half(xo));
        mv_[j] = __builtin_bit_cast(short, __float2half(mm[j]));
        dl_[j] = __builtin_bit_cast(short, __float2half(dd[j]));
      }
      const int ta = r * 128 + ((s * 16) ^ swz);
      *(s16x8*)(plds + ta) = xe_;
      *(s16x8*)(plds + 8192 + ta) = mv_;
      *(s16x8*)(plds + 16384 + ta) = dl_;
    }
  }
  __syncthreads();

  const int l = tid & 63;
  const int rt = tid >> 6;
  f16x8v xe0, xe1, mm0, mm1, dl0, dl1;
  {
    const int r = rt * 16 + (l & 15);
    const int swz = (r & 7) << 4;
    const int s0 = ((l >> 4) * 16) ^ swz;
    const int s1 = (((l >> 4) + 4) * 16) ^ swz;
    xe0 = *(const f16x8v*)(plds + r * 128 + s0);
    xe1 = *(const f16x8v*)(plds + r * 128 + s1);
    mm0 = *(const f16x8v*)(plds + 8192 + r * 128 + s0);
    mm1 = *(const f16x8v*)(plds + 8192 + r * 128 + s1);
    dl0 = *(const f16x8v*)(plds + 16384 + r * 128 + s0);
    dl1 = *(const f16x8v*)(plds + 16384 + r * 128 + s1);
  }

  const s16x8* Wb = (const s16x8*)g_W16;
  const int cj = (l >> 4) * 4;
  const int row = rowbase + rt * 16 + (l & 15);
  unsigned short* Aout = (unsigned short*)A + (size_t)row * 512;
#pragma unroll 4
  for (int ct = 0; ct < 32; ++ct) {
    const int g = ct >> 3, ctl = ct & 7;
    f32x4 acc = {0.f, 0.f, 0.f, 0.f};
    if (g == 0) {
      s16x8 B0 = Wb[(ctl * 2 + 0) * 64 + l];
      s16x8 B1 = Wb[(ctl * 2 + 1) * 64 + l];
      acc = MFH2(B0, dl0, acc);
      acc = MFH2(B1, dl1, acc);
    } else {
      const int mx = 2 * g - 1, mmat = 2 * g;
      s16x8 Bx0 = Wb[((mx * 8 + ctl) * 2 + 0) * 64 + l];
      s16x8 Bx1 = Wb[((mx * 8 + ctl) * 2 + 1) * 64 + l];
      s16x8 Bm0 = Wb[((mmat * 8 + ctl) * 2 + 0) * 64 + l];
      s16x8 Bm1 = Wb[((mmat * 8 + ctl) * 2 + 1) * 64 + l];
      acc = MFH2(Bx0, xe0, acc);
      acc = MFH2(Bx1, xe1, acc);
      acc = MFH2(Bm0, mm0, acc);
      acc = MFH2(Bm1, mm1, acc);
    }
    const f32x4 bv = *(const f32x4*)(g_bias + ct * 16 + cj);
    h16x4 outv;
#pragma unroll
    for (int j = 0; j < 4; ++j) {
      float v = acc[j] + bv[j];
      if (ct < 8) v = __expf(-fmaxf(v, 0.f));
      outv[j] = (_Float16)v;
    }
    *(h16x4*)(Aout + g * 128 + ctl * 16 + cj) = outv;
  }
}

// ---------------------------------------------------------------------------
// Kernel 2: MFMA recurrence, r9's 8-wave structure + fp16 + acc-init +
// cvt_pkrtz packed writes. 16 blocks x 16 batches, 512 threads.
// Wave w owns cols [w*16, w*16+16). D[n][m]=sum_k W[k][n]*h[m][k].
// off_rd: tau*1024 + lane*16 (linear, conflict-free);
// off_wr (bijective, verified r7-r10): (w,b,q) ->
//   (w>>1)*1024 + (b+16*((2w+(q>>1))&3))*16 + 8*(q&1).
// Acc-init: Dz0/Dr0/Dh0 start at the A pre-activation values (C-operand),
// consuming CUR before its depth-4 re-issue -> no copies, no post-adds.
// ---------------------------------------------------------------------------
#define STEP(T0, CUR, NXT)                                                  \
  do {                                                                      \
    const int t_ = (T0);                                                    \
    f32x4 Dz0 = {(float)CUR[1][0], (float)CUR[1][1],                        \
                 (float)CUR[1][2], (float)CUR[1][3]};                       \
    f32x4 Dr0 = {(float)CUR[2][0], (float)CUR[2][1],                        \
                 (float)CUR[2][2], (float)CUR[2][3]};                       \
    f32x4 Dh0 = {(float)CUR[3][0], (float)CUR[3][1],                        \
                 (float)CUR[3][2], (float)CUR[3][3]};                       \
    { /* re-issue CUR <- rows t+4 */                                        \
      const int t4 = (t_ + 4 < T_) ? t_ + 4 : T_ - 1;                       \
      const size_t r = ((size_t)bg * T_ + t4) * 128 + ci;                   \
      CUR[0] = Arows[r];       CUR[1] = Arows[r + 32];                      \
      CUR[2] = Arows[r + 64];  CUR[3] = Arows[r + 96];                      \
    }                                                                       \
    f32x4 Dz1 = {0, 0, 0, 0}, Dr1 = {0, 0, 0, 0};                           \
    {                                                                       \
      s16x8 bh0 = *(const s16x8*)(h_bf + off_rd[0]);                        \
      s16x8 bh1 = *(const s16x8*)(h_bf + off_rd[1]);                        \
      s16x8 bh2 = *(const s16x8*)(h_bf + off_rd[2]);                        \
      s16x8 bh3 = *(const s16x8*)(h_bf + off_rd[3]);                        \
      Dz0 = MFH(wzf[0], bh0, Dz0); Dr0 = MFH(wrf[0], bh0, Dr0);             \
      Dz1 = MFH(wzf[2], bh2, Dz1); Dr1 = MFH(wrf[2], bh2, Dr1);             \
      Dz0 = MFH(wzf[1], bh1, Dz0); Dr0 = MFH(wrf[1], bh1, Dr0);             \
      Dz1 = MFH(wzf[3], bh3, Dz1); Dr1 = MFH(wrf[3], bh3, Dr1);             \
    }                                                                       \
    f32x4 zz;                                                               \
    {                                                                       \
      float r0_ = fsig(Dr0[0] + Dr1[0]) * hsc[0];                           \
      float r1_ = fsig(Dr0[1] + Dr1[1]) * hsc[1];                           \
      float r2_ = fsig(Dr0[2] + Dr1[2]) * hsc[2];                           \
      float r3_ = fsig(Dr0[3] + Dr1[3]) * hsc[3];                           \
      zz[0] = fsig(Dz0[0] + Dz1[0]); zz[1] = fsig(Dz0[1] + Dz1[1]);         \
      zz[2] = fsig(Dz0[2] + Dz1[2]); zz[3] = fsig(Dz0[3] + Dz1[3]);         \
      union { fp16x2 h2[2]; s16x4 v; } u;                                   \
      u.h2[0] = __builtin_amdgcn_cvt_pkrtz(r0_, r1_);                       \
      u.h2[1] = __builtin_amdgcn_cvt_pkrtz(r2_, r3_);                       \
      *(s16x4*)(rh_bf + off_wr) = u.v;                                      \
    }                                                                       \
    BAR();                                                                  \
    f32x4 Dh1 = {0, 0, 0, 0};                                               \
    {                                                                       \
      s16x8 p0 = *(const s16x8*)(rh_bf + off_rd[0]);                        \
      s16x8 p1 = *(const s16x8*)(rh_bf + off_rd[1]);                        \
      s16x8 p2 = *(const s16x8*)(rh_bf + off_rd[2]);                        \
      s16x8 p3 = *(const s16x8*)(rh_bf + off_rd[3]);                        \
      Dh0 = MFH(whf[0], p0, Dh0); Dh1 = MFH(whf[2], p2, Dh1);               \
      Dh0 = MFH(whf[1], p1, Dh0); Dh1 = MFH(whf[3], p3, Dh1);               \
    }                                                                       \
    f32x4 hnv, hgv;                                                         \
    _Pragma("unroll")                                                       \
    for (int j = 0; j < 4; ++j) {                                           \
      float ht = ftanh(Dh0[j] + Dh1[j]);                                    \
      float hn = hsc[j] + zz[j] * (ht - hsc[j]);                            \
      hnv[j] = hn;                                                          \
      float hg = hn * (float)NXT[0][j]; /* fold gamma_h(t+1) */             \
      hgv[j] = hg;                                                          \
      hsc[j] = hg;                                                          \
    }                                                                       \
    {                                                                       \
      union { fp16x2 h2[2]; s16x4 v; } u;                                   \
      u.h2[0] = __builtin_amdgcn_cvt_pkrtz(hgv[0], hgv[1]);                 \
      u.h2[1] = __builtin_amdgcn_cvt_pkrtz(hgv[2], hgv[3]);                 \
      *(s16x4*)(h_bf + off_wr) = u.v;                                       \
    }                                                                       \
    *(f32x4*)(hid + ((size_t)bg * T_ + t_) * H_ + cb) = hnv;                \
    if (t_ == T_ - 1) *(f32x4*)(hlast + (size_t)bg * H_ + cb) = hnv;        \
    BAR();                                                                  \
  } while (0)

__global__ __launch_bounds__(512, 1) void grud_rec_mfma(
    const __half* __restrict__ A, const float* __restrict__ w_zh,
    const float* __restrict__ w_rh, const float* __restrict__ w_hh,
    float* __restrict__ hid, float* __restrict__ hlast) {
  const int tid = threadIdx.x;
  const int w = tid >> 6;
  const int lane = tid & 63;
  const int b = lane & 15;
  const int q = lane >> 4;
  const int cb = w * 16 + q * 4;
  const int bg = blockIdx.x * BB + b;

  __shared__ __align__(16) char lds[8192];
  char* h_bf = lds;
  char* rh_bf = lds + 4096;

  // fp16 A-frags: frag tau, reg j = W[q*8+j+32*tau][w*16+b]
  s16x8 wzf[4], wrf[4], whf[4];
#pragma unroll
  for (int tau = 0; tau < 4; ++tau) {
    s16x8 az, ar, ah;
#pragma unroll
    for (int j = 0; j < 8; ++j) {
      const int k = q * 8 + j + 32 * tau;
      az[j] = __builtin_bit_cast(short, (_Float16)w_zh[k * H_ + w * 16 + b]);
      ar[j] = __builtin_bit_cast(short, (_Float16)w_rh[k * H_ + w * 16 + b]);
      ah[j] = __builtin_bit_cast(short, (_Float16)w_hh[k * H_ + w * 16 + b]);
    }
    wzf[tau] = az; wrf[tau] = ar; whf[tau] = ah;
  }

  for (int i = tid; i < 8192 / 16; i += 512)
    ((f32x4*)lds)[i] = f32x4{0.f, 0.f, 0.f, 0.f};

  int off_rd[4];
#pragma unroll
  for (int tau = 0; tau < 4; ++tau) off_rd[tau] = tau * 1024 + lane * 16;
  const int off_wr =
      (w >> 1) * 1024 + (b + 16 * ((2 * w + (q >> 1)) & 3)) * 16 + 8 * (q & 1);

  const h16x4* Arows = (const h16x4*)A;
  const int ci = cb >> 2;

  h16x4 b0[4], b1[4], b2[4], b3[4];
  {
    const size_t r0 = ((size_t)bg * T_ + 0) * 128 + ci;
    b0[0] = Arows[r0]; b0[1] = Arows[r0 + 32];
    b0[2] = Arows[r0 + 64]; b0[3] = Arows[r0 + 96];
    const size_t r1 = ((size_t)bg * T_ + 1) * 128 + ci;
    b1[0] = Arows[r1]; b1[1] = Arows[r1 + 32];
    b1[2] = Arows[r1 + 64]; b1[3] = Arows[r1 + 96];
    const size_t r2 = ((size_t)bg * T_ + 2) * 128 + ci;
    b2[0] = Arows[r2]; b2[1] = Arows[r2 + 32];
    b2[2] = Arows[r2 + 64]; b2[3] = Arows[r2 + 96];
    const size_t r3 = ((size_t)bg * T_ + 3) * 128 + ci;
    b3[0] = Arows[r3]; b3[1] = Arows[r3 + 32];
    b3[2] = Arows[r3 + 64]; b3[3] = Arows[r3 + 96];
  }
  f32x4 hsc = {0.f, 0.f, 0.f, 0.f};
  __syncthreads();

  for (int tp = 0; tp < T_; tp += 4) {
    STEP(tp + 0, b0, b1);
    STEP(tp + 1, b1, b2);
    STEP(tp + 2, b2, b3);
    STEP(tp + 3, b3, b0);
  }
}

extern "C" void kernel_launch(void* const* d_in, const int* in_sizes, int n_in,
                              void* d_out, int out_size, void* d_ws, size_t ws_size,
                              hipStream_t stream) {
  const float* values = (const float*)d_in[0];
  const float* masks = (const float*)d_in[1];
  const float* deltas = (const float*)d_in[2];
  const float* emean = (const float*)d_in[3];
  const float* locf = (const float*)d_in[4];
  const float* w_gamma_x = (const float*)d_in[5];
  const float* w_gamma_h = (const float*)d_in[6];
  const float* w_rx = (const float*)d_in[7];
  const float* w_rh = (const float*)d_in[8];
  const float* w_rm = (const float*)d_in[9];
  const float* w_zx = (const float*)d_in[10];
  const float* w_zh = (const float*)d_in[11];
  const float* w_zm = (const float*)d_in[12];
  const float* w_hx = (const float*)d_in[13];
  const float* w_hh = (const float*)d_in[14];
  const float* w_hm = (const float*)d_in[15];
  const float* b_gamma_x = (const float*)d_in[16];
  const float* b_gamma_h = (const float*)d_in[17];
  const float* b_r = (const float*)d_in[18];
  const float* b_z = (const float*)d_in[19];
  const float* b_h = (const float*)d_in[20];

  float* hid = (float*)d_out;
  float* hlast = hid + (size_t)B_ * T_ * H_;
  __half* A = (__half*)d_ws;

  wprep<<<dim3(120), dim3(64), 0, stream>>>(
      w_gamma_h, w_zx, w_zm, w_rx, w_rm, w_hx, w_hm, b_gamma_h, b_z, b_r, b_h);
  grud_pre_mfma<<<dim3(B_ * T_ / 64), dim3(256), 0, stream>>>(
      values, masks, deltas, emean, locf, w_gamma_x, b_gamma_x, A);
  grud_rec_mfma<<<dim3(B_ / BB), dim3(512), 0, stream>>>(A, w_zh, w_rh, w_hh,
                                                         hid, hlast);
}